// Round 5
// baseline (2125.037 us; speedup 1.0000x reference)
//
#include <hip/hip_runtime.h>

#define DIM 64
#define XS_STRIDE 192
#define BN_EPS 1e-5f
#define SCAN_CHUNK 1024

// ---------------- setup: zero counts, cursor, stats ----------------
__global__ void setup_kernel(int* __restrict__ counts, int* __restrict__ cursor, int N,
                             float* __restrict__ stats) {
    int gid = blockIdx.x * blockDim.x + threadIdx.x;
    int stride = gridDim.x * blockDim.x;
    for (int i = gid; i < N; i += stride) { counts[i] = 0; cursor[i] = 0; }
    if (gid < 3 * 256) stats[gid] = 0.f;
}

// ---------------- histogram of dst ----------------
__global__ void hist_kernel(const int* __restrict__ edges, long long E, int* __restrict__ counts) {
    long long e = (long long)blockIdx.x * 256 + threadIdx.x;
    if (e >= E) return;
    atomicAdd(&counts[edges[E + e]], 1);
}

// ---------------- scan step 1: per-chunk sums ----------------
__global__ void scan1_kernel(const int* __restrict__ counts, int N, int* __restrict__ partials) {
    __shared__ int red[256];
    int b = blockIdx.x, t = threadIdx.x;
    int base = b * SCAN_CHUNK;
    int s = 0;
    for (int i = t; i < SCAN_CHUNK; i += 256) {
        int idx = base + i;
        s += (idx < N) ? counts[idx] : 0;
    }
    red[t] = s; __syncthreads();
    for (int o = 128; o > 0; o >>= 1) { if (t < o) red[t] += red[t + o]; __syncthreads(); }
    if (t == 0) partials[b] = red[0];
}

// ---------------- scan step 2: exclusive scan of partials (tiny) ----------------
__global__ void scan2_kernel(int* __restrict__ partials, int nb, int* __restrict__ offsets_end) {
    if (threadIdx.x == 0) {
        int acc = 0;
        for (int i = 0; i < nb; i++) { int v = partials[i]; partials[i] = acc; acc += v; }
        *offsets_end = acc;   // offsets[N] = E
    }
}

// ---------------- scan step 3: chunk-local exclusive scan -> offsets ----------------
__global__ void scan3_kernel(const int* __restrict__ counts, int N,
                             const int* __restrict__ partials, int* __restrict__ offsets) {
    __shared__ int sbuf[2][256];
    int b = blockIdx.x, t = threadIdx.x;
    int base = b * SCAN_CHUNK;
    int v[4]; int s = 0;
    #pragma unroll
    for (int j = 0; j < 4; j++) {
        int idx = base + t * 4 + j;
        v[j] = (idx < N) ? counts[idx] : 0;
        s += v[j];
    }
    sbuf[0][t] = s; __syncthreads();
    int cur = 0;
    for (int o = 1; o < 256; o <<= 1) {
        int val = sbuf[cur][t];
        if (t >= o) val += sbuf[cur][t - o];
        sbuf[cur ^ 1][t] = val; __syncthreads(); cur ^= 1;
    }
    int excl = sbuf[cur][t] - s;
    int off = partials[b] + excl;
    #pragma unroll
    for (int j = 0; j < 4; j++) {
        int idx = base + t * 4 + j;
        if (idx < N) offsets[idx] = off;
        off += v[j];
    }
}

// ---- fill CSR: packed entry = src | (dst_local5 << 20); src fits 20 bits (N < 1M) ----
__global__ void fill_kernel(const int* __restrict__ edges, long long E,
                            const int* __restrict__ offsets, int* __restrict__ cursor,
                            int* __restrict__ eidx) {
    long long e = (long long)blockIdx.x * 256 + threadIdx.x;
    if (e >= E) return;
    int src = edges[e];
    int dst = edges[E + e];
    int pos = atomicAdd(&cursor[dst], 1);
    eidx[offsets[dst] + pos] = src | ((dst & 31) << 20);
}

// ---------------- y = h @ w1  (projection before aggregation) ----------------
template<int DIN>
__global__ __launch_bounds__(256) void proj_kernel(
    const float* __restrict__ h, int h_stride, int h_off,
    const float* __restrict__ w1,
    float* __restrict__ y, int N)
{
    constexpr int R = 32;
    __shared__ float w1s[DIN * DIM];
    __shared__ float hin[R][DIN];
    const int tid = threadIdx.x;
    const int row0 = blockIdx.x * R;

    for (int i = tid; i < DIN * DIM; i += 256) w1s[i] = w1[i];
    for (int i = tid; i < R * DIN; i += 256) {
        int r = i / DIN, k = i % DIN;
        int row = row0 + r;
        hin[r][k] = (row < N) ? h[(size_t)row * h_stride + h_off + k] : 0.f;
    }
    __syncthreads();

    const int c  = tid & 63;
    const int rg = tid >> 6;
    float acc[8];
    #pragma unroll
    for (int i = 0; i < 8; i++) acc[i] = 0.f;
    for (int k = 0; k < DIN; k++) {
        float wv = w1s[k * DIM + c];
        #pragma unroll
        for (int i = 0; i < 8; i++) acc[i] += hin[rg + 4 * i][k] * wv;
    }
    #pragma unroll
    for (int i = 0; i < 8; i++) {
        int row = row0 + rg + 4 * i;
        if (row < N) y[(size_t)row * DIM + c] = acc[i];
    }
}

// ---- fused: zin = y[self] + b1 + edge-parallel LDS-atomic gather; relu; @w2+b2; relu ----
__global__ __launch_bounds__(256) void aggmlp_kernel(
    const float* __restrict__ y,
    const int* __restrict__ offsets, const int* __restrict__ eidx,
    const float* __restrict__ b1,
    const float* __restrict__ w2, const float* __restrict__ b2,
    float* __restrict__ xs, int xs_off,
    float* __restrict__ stats, int N)
{
    constexpr int R = 32;
    __shared__ float w2s[DIM * DIM];     // 16KB
    __shared__ float zin[R][DIM];        // 8KB
    __shared__ float sred[2][DIM];
    const int tid  = threadIdx.x;
    const int row0 = blockIdx.x * R;
    const int lane = tid & 63;
    const int wv_  = tid >> 6;

    for (int i = tid; i < DIM * DIM; i += 256) w2s[i] = w2[i];
    if (tid < DIM) { sred[0][tid] = 0.f; sred[1][tid] = 0.f; }

    // phase 1: init zin with self contribution + b1
    #pragma unroll
    for (int r = wv_; r < R; r += 4) {
        int node = row0 + r;
        zin[r][lane] = (node < N) ? y[(size_t)node * DIM + lane] + b1[lane] : 0.f;
    }
    __syncthreads();

    // phase 2: edge-parallel gather; block's CSR range is contiguous
    {
        const int base = offsets[row0];
        const int end  = offsets[min(row0 + R, N)];
        const int tot  = end - base;
        const int per  = (tot + 3) >> 2;
        int es = base + wv_ * per;
        int ee = min(es + per, end);
        #pragma unroll 8
        for (int e = es; e < ee; e++) {
            int v   = eidx[e];
            int src = v & 0xFFFFF;
            int r   = v >> 20;
            atomicAdd(&zin[r][lane], y[(size_t)src * DIM + lane]);
        }
    }
    __syncthreads();

    // phase 3: relu in place
    {
        float* zf = &zin[0][0];
        #pragma unroll
        for (int i = tid; i < R * DIM; i += 256) zf[i] = fmaxf(zf[i], 0.f);
    }
    __syncthreads();

    // phase 4: GEMM relu(z) @ w2 + b2, register-tiled (8 rows/thread)
    float acc[8];
    #pragma unroll
    for (int i = 0; i < 8; i++) acc[i] = b2[lane];
    for (int k = 0; k < DIM; k++) {
        float w = w2s[k * DIM + lane];
        #pragma unroll
        for (int i = 0; i < 8; i++) acc[i] += zin[wv_ + 4 * i][k] * w;
    }
    float s1 = 0.f, s2 = 0.f;
    #pragma unroll
    for (int i = 0; i < 8; i++) {
        int row = row0 + wv_ + 4 * i;
        if (row < N) {
            float v = fmaxf(acc[i], 0.f);   // F.relu after conv
            xs[(size_t)row * XS_STRIDE + xs_off + lane] = v;
            s1 += v; s2 += v * v;
        }
    }
    atomicAdd(&sred[0][lane], s1);
    atomicAdd(&sred[1][lane], s2);
    __syncthreads();
    if (tid < DIM) {
        atomicAdd(&stats[tid], sred[0][tid]);
        atomicAdd(&stats[DIM + tid], sred[1][tid]);
    }
}

// ---------------- BN params: scale/shift from sum/sumsq ----------------
__global__ void bnparam_kernel(const float* __restrict__ stats,
                               const float* __restrict__ gamma, const float* __restrict__ beta,
                               float* __restrict__ sc, int N) {
    int c = threadIdx.x;  // 64 threads
    float inv_n = 1.0f / (float)N;
    float mean = stats[c] * inv_n;
    float var  = stats[DIM + c] * inv_n - mean * mean;
    float scale = gamma[c] * rsqrtf(var + BN_EPS);
    sc[c] = scale;
    sc[DIM + c] = beta[c] - mean * scale;
}

// ---------------- in-place BN normalize of xs columns ----------------
__global__ void norm_kernel(float* __restrict__ xs, const float* __restrict__ sc,
                            int xs_off, int N) {
    int gid = blockIdx.x * blockDim.x + threadIdx.x;
    if (gid >= N * DIM) return;
    int n = gid >> 6, c = gid & 63;
    size_t p = (size_t)n * XS_STRIDE + xs_off + c;
    xs[p] = xs[p] * sc[c] + sc[DIM + c];
}

// ---------------- per-graph pooling (batch sorted -> binary search) ----------------
__global__ void pool_kernel(const float* __restrict__ xs, const int* __restrict__ batch,
                            float* __restrict__ pool, int N) {
    int g = blockIdx.x;
    int tid = threadIdx.x;  // 192 threads
    int lo = 0, hi = N;
    while (lo < hi) { int mid = (lo + hi) >> 1; if (batch[mid] < g) lo = mid + 1; else hi = mid; }
    int start = lo;
    hi = N;
    while (lo < hi) { int mid = (lo + hi) >> 1; if (batch[mid] < g + 1) lo = mid + 1; else hi = mid; }
    int end = lo;
    float s = 0.f;
    for (int n = start; n < end; n++) s += xs[(size_t)n * XS_STRIDE + tid];
    pool[(size_t)g * XS_STRIDE + tid] = s;
}

extern "C" void kernel_launch(void* const* d_in, const int* in_sizes, int n_in,
                              void* d_out, int out_size, void* d_ws, size_t ws_size,
                              hipStream_t stream) {
    const float* x     = (const float*)d_in[0];
    const int*   edges = (const int*)d_in[1];   // int32 (harness converts integer inputs)
    const int*   batch = (const int*)d_in[2];   // int32

    const int  N    = in_sizes[2];
    const long long E = in_sizes[1] / 2;
    const int  F_IN = in_sizes[0] / N;              // 128
    const int  G    = out_size / XS_STRIDE - N;     // 1000

    const float* W[3][6];
    for (int l = 0; l < 3; l++)
        for (int p = 0; p < 6; p++)
            W[l][p] = (const float*)d_in[4 + l * 6 + p];

    float* out_pool = (float*)d_out;                        // G x 192
    float* out_xs   = out_pool + (size_t)G * XS_STRIDE;     // N x 192

    // workspace layout (~33 MB)
    float* y       = (float*)d_ws;                      // N x 64 (25.6 MB)
    float* stats   = y + (size_t)N * DIM;               // 3 x 256 floats
    int*   counts  = (int*)(stats + 3 * 256);           // N
    int*   cursor  = counts + N;                        // N
    int*   offsets = cursor + N;                        // N + 1
    int*   partials= offsets + N + 1;                   // ~128
    int*   eidx    = partials + 256;                    // E (6.4 MB)

    const int eblk   = (int)((E + 255) / 256);
    const int nscan  = (N + SCAN_CHUNK - 1) / SCAN_CHUNK;
    const int mblocks = (N + 31) / 32;
    const int nblocks = (N * DIM + 255) / 256;

    // ---- build CSR once (shared by all 3 layers) ----
    setup_kernel<<<512, 256, 0, stream>>>(counts, cursor, N, stats);
    hist_kernel<<<eblk, 256, 0, stream>>>(edges, E, counts);
    scan1_kernel<<<nscan, 256, 0, stream>>>(counts, N, partials);
    scan2_kernel<<<1, 64, 0, stream>>>(partials, nscan, offsets + N);
    scan3_kernel<<<nscan, 256, 0, stream>>>(counts, N, partials, offsets);
    fill_kernel<<<eblk, 256, 0, stream>>>(edges, E, offsets, cursor, eidx);

    for (int l = 0; l < 3; l++) {
        const float* h     = (l == 0) ? x : out_xs;
        const int h_stride = (l == 0) ? F_IN : XS_STRIDE;
        const int h_off    = (l == 0) ? 0 : (l - 1) * DIM;
        float* statsL = stats + l * 256;

        if (l == 0)
            proj_kernel<128><<<mblocks, 256, 0, stream>>>(h, h_stride, h_off, W[l][0], y, N);
        else
            proj_kernel<64><<<mblocks, 256, 0, stream>>>(h, h_stride, h_off, W[l][0], y, N);

        aggmlp_kernel<<<mblocks, 256, 0, stream>>>(y, offsets, eidx,
            W[l][1], W[l][2], W[l][3], out_xs, l * DIM, statsL, N);

        bnparam_kernel<<<1, 64, 0, stream>>>(statsL, W[l][4], W[l][5], statsL + 2 * DIM, N);

        norm_kernel<<<nblocks, 256, 0, stream>>>(out_xs, statsL + 2 * DIM, l * DIM, N);
    }

    pool_kernel<<<G, XS_STRIDE, 0, stream>>>(out_xs, batch, out_pool, N);
}

// Round 6
// 1166.299 us; speedup vs baseline: 1.8220x; 1.8220x over previous
//
#include <hip/hip_runtime.h>

#define DIM 64
#define XS_STRIDE 192
#define BN_EPS 1e-5f
#define SCAN_CHUNK 1024

// ---------------- setup: zero counts, cursor, stats ----------------
__global__ void setup_kernel(int* __restrict__ counts, int* __restrict__ cursor, int N,
                             float* __restrict__ stats) {
    int gid = blockIdx.x * blockDim.x + threadIdx.x;
    int stride = gridDim.x * blockDim.x;
    for (int i = gid; i < N; i += stride) { counts[i] = 0; cursor[i] = 0; }
    if (gid < 3 * 256) stats[gid] = 0.f;
}

// ---------------- histogram of dst ----------------
__global__ void hist_kernel(const int* __restrict__ edges, long long E, int* __restrict__ counts) {
    long long e = (long long)blockIdx.x * 256 + threadIdx.x;
    if (e >= E) return;
    atomicAdd(&counts[edges[E + e]], 1);
}

// ---------------- scan step 1: per-chunk sums ----------------
__global__ void scan1_kernel(const int* __restrict__ counts, int N, int* __restrict__ partials) {
    __shared__ int red[256];
    int b = blockIdx.x, t = threadIdx.x;
    int base = b * SCAN_CHUNK;
    int s = 0;
    for (int i = t; i < SCAN_CHUNK; i += 256) {
        int idx = base + i;
        s += (idx < N) ? counts[idx] : 0;
    }
    red[t] = s; __syncthreads();
    for (int o = 128; o > 0; o >>= 1) { if (t < o) red[t] += red[t + o]; __syncthreads(); }
    if (t == 0) partials[b] = red[0];
}

// ---------------- scan step 2: exclusive scan of partials (tiny) ----------------
__global__ void scan2_kernel(int* __restrict__ partials, int nb, int* __restrict__ offsets_end) {
    if (threadIdx.x == 0) {
        int acc = 0;
        for (int i = 0; i < nb; i++) { int v = partials[i]; partials[i] = acc; acc += v; }
        *offsets_end = acc;   // offsets[N] = E
    }
}

// ---------------- scan step 3: chunk-local exclusive scan -> offsets ----------------
__global__ void scan3_kernel(const int* __restrict__ counts, int N,
                             const int* __restrict__ partials, int* __restrict__ offsets) {
    __shared__ int sbuf[2][256];
    int b = blockIdx.x, t = threadIdx.x;
    int base = b * SCAN_CHUNK;
    int v[4]; int s = 0;
    #pragma unroll
    for (int j = 0; j < 4; j++) {
        int idx = base + t * 4 + j;
        v[j] = (idx < N) ? counts[idx] : 0;
        s += v[j];
    }
    sbuf[0][t] = s; __syncthreads();
    int cur = 0;
    for (int o = 1; o < 256; o <<= 1) {
        int val = sbuf[cur][t];
        if (t >= o) val += sbuf[cur][t - o];
        sbuf[cur ^ 1][t] = val; __syncthreads(); cur ^= 1;
    }
    int excl = sbuf[cur][t] - s;
    int off = partials[b] + excl;
    #pragma unroll
    for (int j = 0; j < 4; j++) {
        int idx = base + t * 4 + j;
        if (idx < N) offsets[idx] = off;
        off += v[j];
    }
}

// ---------------- fill CSR edge index (src ids bucketed by dst) ----------------
__global__ void fill_kernel(const int* __restrict__ edges, long long E,
                            const int* __restrict__ offsets, int* __restrict__ cursor,
                            int* __restrict__ eidx) {
    long long e = (long long)blockIdx.x * 256 + threadIdx.x;
    if (e >= E) return;
    int src = edges[e];
    int dst = edges[E + e];
    int pos = atomicAdd(&cursor[dst], 1);
    eidx[offsets[dst] + pos] = src;
}

// ---------------- y = h @ w1  (projection before aggregation) ----------------
template<int DIN>
__global__ __launch_bounds__(256) void proj_kernel(
    const float* __restrict__ h, int h_stride, int h_off,
    const float* __restrict__ w1,
    float* __restrict__ y, int N)
{
    constexpr int R = 32;
    __shared__ float w1s[DIN * DIM];
    __shared__ float hin[R][DIN];
    const int tid = threadIdx.x;
    const int row0 = blockIdx.x * R;

    for (int i = tid; i < DIN * DIM; i += 256) w1s[i] = w1[i];
    for (int i = tid; i < R * DIN; i += 256) {
        int r = i / DIN, k = i % DIN;
        int row = row0 + r;
        hin[r][k] = (row < N) ? h[(size_t)row * h_stride + h_off + k] : 0.f;
    }
    __syncthreads();

    const int c  = tid & 63;
    const int rg = tid >> 6;
    float acc[8];
    #pragma unroll
    for (int i = 0; i < 8; i++) acc[i] = 0.f;
    for (int k = 0; k < DIN; k++) {
        float wv = w1s[k * DIM + c];
        #pragma unroll
        for (int i = 0; i < 8; i++) acc[i] += hin[rg + 4 * i][k] * wv;
    }
    #pragma unroll
    for (int i = 0; i < 8; i++) {
        int row = row0 + rg + 4 * i;
        if (row < N) y[(size_t)row * DIM + c] = acc[i];
    }
}

// ---- fused: interleaved 8-row gather (8 loads in flight); relu; @w2+b2; relu; stats ----
__global__ __launch_bounds__(256) void aggmlp_kernel(
    const float* __restrict__ y,
    const int* __restrict__ offsets, const int* __restrict__ eidx,
    const float* __restrict__ b1,
    const float* __restrict__ w2, const float* __restrict__ b2,
    float* __restrict__ xs, int xs_off,
    float* __restrict__ stats, int N)
{
    constexpr int R = 32;
    __shared__ float w2s[DIM * DIM];     // 16KB
    __shared__ float zin[R][DIM];        // 8KB
    __shared__ float sred[2][DIM];
    const int tid  = threadIdx.x;
    const int row0 = blockIdx.x * R;
    const int lane = tid & 63;
    const int wv_  = tid >> 6;

    for (int i = tid; i < DIM * DIM; i += 256) w2s[i] = w2[i];
    if (tid < DIM) { sred[0][tid] = 0.f; sred[1][tid] = 0.f; }

    // wave wv_ owns rows wv_, wv_+4, ..., wv_+28; iterate neighbor-position-major
    // so 8 independent gathers are in flight per step.
    int p[8], pe[8];
    float acc[8];
    const float bias = b1[lane];
    #pragma unroll
    for (int i = 0; i < 8; i++) {
        int node = row0 + wv_ + 4 * i;
        if (node < N) {
            p[i]  = offsets[node];
            pe[i] = offsets[node + 1];
            acc[i] = y[(size_t)node * DIM + lane] + bias;
        } else { p[i] = 0; pe[i] = 0; acc[i] = 0.f; }
    }
    int steps = 0;
    #pragma unroll
    for (int i = 0; i < 8; i++) steps = max(steps, pe[i] - p[i]);
    for (int s = 0; s < steps; s++) {
        float v[8];
        #pragma unroll
        for (int i = 0; i < 8; i++)
            v[i] = (p[i] < pe[i]) ? y[(size_t)eidx[p[i]] * DIM + lane] : 0.f;
        #pragma unroll
        for (int i = 0; i < 8; i++) {
            acc[i] += v[i];
            p[i] += (p[i] < pe[i]) ? 1 : 0;
        }
    }
    #pragma unroll
    for (int i = 0; i < 8; i++)
        zin[wv_ + 4 * i][lane] = fmaxf(acc[i], 0.f);   // relu between linear layers
    __syncthreads();

    // GEMM: relu(z) @ w2 + b2, register-tiled (8 rows/thread)
    float oacc[8];
    #pragma unroll
    for (int i = 0; i < 8; i++) oacc[i] = b2[lane];
    for (int k = 0; k < DIM; k++) {
        float w = w2s[k * DIM + lane];
        #pragma unroll
        for (int i = 0; i < 8; i++) oacc[i] += zin[wv_ + 4 * i][k] * w;
    }
    float s1 = 0.f, s2 = 0.f;
    #pragma unroll
    for (int i = 0; i < 8; i++) {
        int row = row0 + wv_ + 4 * i;
        if (row < N) {
            float v = fmaxf(oacc[i], 0.f);   // F.relu after conv
            xs[(size_t)row * XS_STRIDE + xs_off + lane] = v;
            s1 += v; s2 += v * v;
        }
    }
    atomicAdd(&sred[0][lane], s1);
    atomicAdd(&sred[1][lane], s2);
    __syncthreads();
    if (tid < DIM) {
        atomicAdd(&stats[tid], sred[0][tid]);
        atomicAdd(&stats[DIM + tid], sred[1][tid]);
    }
}

// ---------------- BN params: scale/shift from sum/sumsq ----------------
__global__ void bnparam_kernel(const float* __restrict__ stats,
                               const float* __restrict__ gamma, const float* __restrict__ beta,
                               float* __restrict__ sc, int N) {
    int c = threadIdx.x;  // 64 threads
    float inv_n = 1.0f / (float)N;
    float mean = stats[c] * inv_n;
    float var  = stats[DIM + c] * inv_n - mean * mean;
    float scale = gamma[c] * rsqrtf(var + BN_EPS);
    sc[c] = scale;
    sc[DIM + c] = beta[c] - mean * scale;
}

// ---------------- in-place BN normalize of xs columns ----------------
__global__ void norm_kernel(float* __restrict__ xs, const float* __restrict__ sc,
                            int xs_off, int N) {
    int gid = blockIdx.x * blockDim.x + threadIdx.x;
    if (gid >= N * DIM) return;
    int n = gid >> 6, c = gid & 63;
    size_t p = (size_t)n * XS_STRIDE + xs_off + c;
    xs[p] = xs[p] * sc[c] + sc[DIM + c];
}

// ---------------- per-graph pooling (batch sorted -> binary search) ----------------
__global__ void pool_kernel(const float* __restrict__ xs, const int* __restrict__ batch,
                            float* __restrict__ pool, int N) {
    int g = blockIdx.x;
    int tid = threadIdx.x;  // 192 threads
    int lo = 0, hi = N;
    while (lo < hi) { int mid = (lo + hi) >> 1; if (batch[mid] < g) lo = mid + 1; else hi = mid; }
    int start = lo;
    hi = N;
    while (lo < hi) { int mid = (lo + hi) >> 1; if (batch[mid] < g + 1) lo = mid + 1; else hi = mid; }
    int end = lo;
    float s = 0.f;
    for (int n = start; n < end; n++) s += xs[(size_t)n * XS_STRIDE + tid];
    pool[(size_t)g * XS_STRIDE + tid] = s;
}

extern "C" void kernel_launch(void* const* d_in, const int* in_sizes, int n_in,
                              void* d_out, int out_size, void* d_ws, size_t ws_size,
                              hipStream_t stream) {
    const float* x     = (const float*)d_in[0];
    const int*   edges = (const int*)d_in[1];   // int32 (harness converts integer inputs)
    const int*   batch = (const int*)d_in[2];   // int32

    const int  N    = in_sizes[2];
    const long long E = in_sizes[1] / 2;
    const int  F_IN = in_sizes[0] / N;              // 128
    const int  G    = out_size / XS_STRIDE - N;     // 1000

    const float* W[3][6];
    for (int l = 0; l < 3; l++)
        for (int p = 0; p < 6; p++)
            W[l][p] = (const float*)d_in[4 + l * 6 + p];

    float* out_pool = (float*)d_out;                        // G x 192
    float* out_xs   = out_pool + (size_t)G * XS_STRIDE;     // N x 192

    // workspace layout (~33 MB)
    float* y       = (float*)d_ws;                      // N x 64 (25.6 MB)
    float* stats   = y + (size_t)N * DIM;               // 3 x 256 floats
    int*   counts  = (int*)(stats + 3 * 256);           // N
    int*   cursor  = counts + N;                        // N
    int*   offsets = cursor + N;                        // N + 1
    int*   partials= offsets + N + 1;                   // ~128
    int*   eidx    = partials + 256;                    // E (6.4 MB)

    const int eblk   = (int)((E + 255) / 256);
    const int nscan  = (N + SCAN_CHUNK - 1) / SCAN_CHUNK;
    const int mblocks = (N + 31) / 32;
    const int nblocks = (N * DIM + 255) / 256;

    // ---- build CSR once (shared by all 3 layers) ----
    setup_kernel<<<512, 256, 0, stream>>>(counts, cursor, N, stats);
    hist_kernel<<<eblk, 256, 0, stream>>>(edges, E, counts);
    scan1_kernel<<<nscan, 256, 0, stream>>>(counts, N, partials);
    scan2_kernel<<<1, 64, 0, stream>>>(partials, nscan, offsets + N);
    scan3_kernel<<<nscan, 256, 0, stream>>>(counts, N, partials, offsets);
    fill_kernel<<<eblk, 256, 0, stream>>>(edges, E, offsets, cursor, eidx);

    for (int l = 0; l < 3; l++) {
        const float* h     = (l == 0) ? x : out_xs;
        const int h_stride = (l == 0) ? F_IN : XS_STRIDE;
        const int h_off    = (l == 0) ? 0 : (l - 1) * DIM;
        float* statsL = stats + l * 256;

        if (l == 0)
            proj_kernel<128><<<mblocks, 256, 0, stream>>>(h, h_stride, h_off, W[l][0], y, N);
        else
            proj_kernel<64><<<mblocks, 256, 0, stream>>>(h, h_stride, h_off, W[l][0], y, N);

        aggmlp_kernel<<<mblocks, 256, 0, stream>>>(y, offsets, eidx,
            W[l][1], W[l][2], W[l][3], out_xs, l * DIM, statsL, N);

        bnparam_kernel<<<1, 64, 0, stream>>>(statsL, W[l][4], W[l][5], statsL + 2 * DIM, N);

        norm_kernel<<<nblocks, 256, 0, stream>>>(out_xs, statsL + 2 * DIM, l * DIM, N);
    }

    pool_kernel<<<G, XS_STRIDE, 0, stream>>>(out_xs, batch, out_pool, N);
}

// Round 7
// 1081.432 us; speedup vs baseline: 1.9650x; 1.0785x over previous
//
#include <hip/hip_runtime.h>

#define DIM 64
#define XS_STRIDE 192
#define BN_EPS 1e-5f
#define SCAN_CHUNK 1024

__device__ inline unsigned pack_bf16x2(float lo, float hi) {
    unsigned ulo = __float_as_uint(lo); ulo = (ulo + 0x7FFFu + ((ulo >> 16) & 1u)) >> 16;
    unsigned uhi = __float_as_uint(hi); uhi = (uhi + 0x7FFFu + ((uhi >> 16) & 1u)) >> 16;
    return ulo | (uhi << 16);
}
__device__ inline float2 unpack_bf16x2(unsigned v) {
    return make_float2(__uint_as_float(v << 16), __uint_as_float(v & 0xFFFF0000u));
}

// ---------------- setup: zero counts, cursor, stats ----------------
__global__ void setup_kernel(int* __restrict__ counts, int* __restrict__ cursor, int N,
                             float* __restrict__ stats) {
    int gid = blockIdx.x * blockDim.x + threadIdx.x;
    int stride = gridDim.x * blockDim.x;
    for (int i = gid; i < N; i += stride) { counts[i] = 0; cursor[i] = 0; }
    if (gid < 3 * 256) stats[gid] = 0.f;
}

// ---------------- histogram of dst ----------------
__global__ void hist_kernel(const int* __restrict__ edges, long long E, int* __restrict__ counts) {
    long long e = (long long)blockIdx.x * 256 + threadIdx.x;
    if (e >= E) return;
    atomicAdd(&counts[edges[E + e]], 1);
}

// ---------------- scan step 1: per-chunk sums ----------------
__global__ void scan1_kernel(const int* __restrict__ counts, int N, int* __restrict__ partials) {
    __shared__ int red[256];
    int b = blockIdx.x, t = threadIdx.x;
    int base = b * SCAN_CHUNK;
    int s = 0;
    for (int i = t; i < SCAN_CHUNK; i += 256) {
        int idx = base + i;
        s += (idx < N) ? counts[idx] : 0;
    }
    red[t] = s; __syncthreads();
    for (int o = 128; o > 0; o >>= 1) { if (t < o) red[t] += red[t + o]; __syncthreads(); }
    if (t == 0) partials[b] = red[0];
}

// ---------------- scan step 2: exclusive scan of partials (tiny) ----------------
__global__ void scan2_kernel(int* __restrict__ partials, int nb, int* __restrict__ offsets_end) {
    if (threadIdx.x == 0) {
        int acc = 0;
        for (int i = 0; i < nb; i++) { int v = partials[i]; partials[i] = acc; acc += v; }
        *offsets_end = acc;   // offsets[N] = E
    }
}

// ---------------- scan step 3: chunk-local exclusive scan -> offsets ----------------
__global__ void scan3_kernel(const int* __restrict__ counts, int N,
                             const int* __restrict__ partials, int* __restrict__ offsets) {
    __shared__ int sbuf[2][256];
    int b = blockIdx.x, t = threadIdx.x;
    int base = b * SCAN_CHUNK;
    int v[4]; int s = 0;
    #pragma unroll
    for (int j = 0; j < 4; j++) {
        int idx = base + t * 4 + j;
        v[j] = (idx < N) ? counts[idx] : 0;
        s += v[j];
    }
    sbuf[0][t] = s; __syncthreads();
    int cur = 0;
    for (int o = 1; o < 256; o <<= 1) {
        int val = sbuf[cur][t];
        if (t >= o) val += sbuf[cur][t - o];
        sbuf[cur ^ 1][t] = val; __syncthreads(); cur ^= 1;
    }
    int excl = sbuf[cur][t] - s;
    int off = partials[b] + excl;
    #pragma unroll
    for (int j = 0; j < 4; j++) {
        int idx = base + t * 4 + j;
        if (idx < N) offsets[idx] = off;
        off += v[j];
    }
}

// ---------------- fill CSR edge index (src ids bucketed by dst) ----------------
__global__ void fill_kernel(const int* __restrict__ edges, long long E,
                            const int* __restrict__ offsets, int* __restrict__ cursor,
                            int* __restrict__ eidx) {
    long long e = (long long)blockIdx.x * 256 + threadIdx.x;
    if (e >= E) return;
    int src = edges[e];
    int dst = edges[E + e];
    int pos = atomicAdd(&cursor[dst], 1);
    eidx[offsets[dst] + pos] = src;
}

// ---- y = h @ w1, packed bf16x2: half-wave computes 2 cols x 4 rows ----
template<int DIN>
__global__ __launch_bounds__(256) void proj_kernel(
    const float* __restrict__ h, int h_stride, int h_off,
    const float* __restrict__ w1,
    unsigned* __restrict__ ybf, int N)
{
    constexpr int R = 32;
    __shared__ float w1s[DIN * DIM];
    __shared__ float hin[R][DIN];
    const int tid = threadIdx.x;
    const int row0 = blockIdx.x * R;

    for (int i = tid; i < DIN * DIM; i += 256) w1s[i] = w1[i];
    for (int i = tid; i < R * DIN; i += 256) {
        int r = i / DIN, k = i % DIN;
        int row = row0 + r;
        hin[r][k] = (row < N) ? h[(size_t)row * h_stride + h_off + k] : 0.f;
    }
    __syncthreads();

    const int hw = tid >> 5;       // half-wave 0..7 owns rows hw*4..hw*4+3
    const int hl = tid & 31;       // cols 2*hl, 2*hl+1
    float a0[4], a1[4];
    #pragma unroll
    for (int q = 0; q < 4; q++) { a0[q] = 0.f; a1[q] = 0.f; }
    for (int k = 0; k < DIN; k++) {
        float w0 = w1s[k * DIM + 2 * hl];
        float w1v = w1s[k * DIM + 2 * hl + 1];
        #pragma unroll
        for (int q = 0; q < 4; q++) {
            float hv = hin[hw * 4 + q][k];
            a0[q] += hv * w0; a1[q] += hv * w1v;
        }
    }
    #pragma unroll
    for (int q = 0; q < 4; q++) {
        int row = row0 + hw * 4 + q;
        if (row < N) ybf[(size_t)row * 32 + hl] = pack_bf16x2(a0[q], a1[q]);
    }
}

// ---- fused: half-wave gathers 4 rows (128B bf16 rows); relu; @w2+b2; relu; stats ----
__global__ __launch_bounds__(256) void aggmlp_kernel(
    const unsigned* __restrict__ ybf,
    const int* __restrict__ offsets, const int* __restrict__ eidx,
    const float* __restrict__ b1,
    const float* __restrict__ w2, const float* __restrict__ b2,
    float* __restrict__ xs, int xs_off,
    float* __restrict__ stats, int N)
{
    constexpr int R = 32;
    __shared__ float w2s[DIM * DIM];     // 16KB
    __shared__ float zin[R][DIM];        // 8KB
    __shared__ float sred[2][DIM];
    const int tid  = threadIdx.x;
    const int row0 = blockIdx.x * R;
    const int hw = tid >> 5;             // half-wave 0..7 owns rows hw*4..hw*4+3
    const int hl = tid & 31;             // feature pair (2*hl, 2*hl+1)

    for (int i = tid; i < DIM * DIM; i += 256) w2s[i] = w2[i];
    if (tid < DIM) { sred[0][tid] = 0.f; sred[1][tid] = 0.f; }

    const float b1lo = b1[2 * hl], b1hi = b1[2 * hl + 1];
    float ax[4], ay[4];
    int p[4], pe[4];
    #pragma unroll
    for (int q = 0; q < 4; q++) {
        int node = row0 + hw * 4 + q;
        if (node < N) {
            p[q]  = offsets[node];
            pe[q] = offsets[node + 1];
            float2 s = unpack_bf16x2(ybf[(size_t)node * 32 + hl]);
            ax[q] = s.x + b1lo; ay[q] = s.y + b1hi;
        } else { p[q] = 0; pe[q] = 0; ax[q] = 0.f; ay[q] = 0.f; }
    }
    for (;;) {
        int rem = 0;
        #pragma unroll
        for (int q = 0; q < 4; q++) rem |= (p[q] < pe[q]);
        if (!rem) break;
        #pragma unroll
        for (int q = 0; q < 4; q++) {
            if (p[q] < pe[q]) {
                int src = eidx[p[q]++];
                float2 v = unpack_bf16x2(ybf[(size_t)src * 32 + hl]);
                ax[q] += v.x; ay[q] += v.y;
            }
        }
    }
    #pragma unroll
    for (int q = 0; q < 4; q++) {
        zin[hw * 4 + q][2 * hl]     = fmaxf(ax[q], 0.f);   // relu between linear layers
        zin[hw * 4 + q][2 * hl + 1] = fmaxf(ay[q], 0.f);
    }
    __syncthreads();

    // GEMM: relu(z) @ w2 + b2, register-tiled (8 rows/thread), lane = out col
    const int lane = tid & 63;
    const int wv_  = tid >> 6;
    float oacc[8];
    #pragma unroll
    for (int i = 0; i < 8; i++) oacc[i] = b2[lane];
    for (int k = 0; k < DIM; k++) {
        float w = w2s[k * DIM + lane];
        #pragma unroll
        for (int i = 0; i < 8; i++) oacc[i] += zin[wv_ + 4 * i][k] * w;
    }
    float s1 = 0.f, s2 = 0.f;
    #pragma unroll
    for (int i = 0; i < 8; i++) {
        int row = row0 + wv_ + 4 * i;
        if (row < N) {
            float v = fmaxf(oacc[i], 0.f);   // F.relu after conv
            xs[(size_t)row * XS_STRIDE + xs_off + lane] = v;
            s1 += v; s2 += v * v;
        }
    }
    atomicAdd(&sred[0][lane], s1);
    atomicAdd(&sred[1][lane], s2);
    __syncthreads();
    if (tid < DIM) {
        atomicAdd(&stats[tid], sred[0][tid]);
        atomicAdd(&stats[DIM + tid], sred[1][tid]);
    }
}

// ---------------- BN params: scale/shift from sum/sumsq ----------------
__global__ void bnparam_kernel(const float* __restrict__ stats,
                               const float* __restrict__ gamma, const float* __restrict__ beta,
                               float* __restrict__ sc, int N) {
    int c = threadIdx.x;  // 64 threads
    float inv_n = 1.0f / (float)N;
    float mean = stats[c] * inv_n;
    float var  = stats[DIM + c] * inv_n - mean * mean;
    float scale = gamma[c] * rsqrtf(var + BN_EPS);
    sc[c] = scale;
    sc[DIM + c] = beta[c] - mean * scale;
}

// ---------------- in-place BN normalize of xs columns ----------------
__global__ void norm_kernel(float* __restrict__ xs, const float* __restrict__ sc,
                            int xs_off, int N) {
    int gid = blockIdx.x * blockDim.x + threadIdx.x;
    if (gid >= N * DIM) return;
    int n = gid >> 6, c = gid & 63;
    size_t p = (size_t)n * XS_STRIDE + xs_off + c;
    xs[p] = xs[p] * sc[c] + sc[DIM + c];
}

// ---------------- per-graph pooling (batch sorted -> binary search) ----------------
__global__ void pool_kernel(const float* __restrict__ xs, const int* __restrict__ batch,
                            float* __restrict__ pool, int N) {
    int g = blockIdx.x;
    int tid = threadIdx.x;  // 192 threads
    int lo = 0, hi = N;
    while (lo < hi) { int mid = (lo + hi) >> 1; if (batch[mid] < g) lo = mid + 1; else hi = mid; }
    int start = lo;
    hi = N;
    while (lo < hi) { int mid = (lo + hi) >> 1; if (batch[mid] < g + 1) lo = mid + 1; else hi = mid; }
    int end = lo;
    float s = 0.f;
    for (int n = start; n < end; n++) s += xs[(size_t)n * XS_STRIDE + tid];
    pool[(size_t)g * XS_STRIDE + tid] = s;
}

extern "C" void kernel_launch(void* const* d_in, const int* in_sizes, int n_in,
                              void* d_out, int out_size, void* d_ws, size_t ws_size,
                              hipStream_t stream) {
    const float* x     = (const float*)d_in[0];
    const int*   edges = (const int*)d_in[1];   // int32 (harness converts integer inputs)
    const int*   batch = (const int*)d_in[2];   // int32

    const int  N    = in_sizes[2];
    const long long E = in_sizes[1] / 2;
    const int  F_IN = in_sizes[0] / N;              // 128
    const int  G    = out_size / XS_STRIDE - N;     // 1000

    const float* W[3][6];
    for (int l = 0; l < 3; l++)
        for (int p = 0; p < 6; p++)
            W[l][p] = (const float*)d_in[4 + l * 6 + p];

    float* out_pool = (float*)d_out;                        // G x 192
    float* out_xs   = out_pool + (size_t)G * XS_STRIDE;     // N x 192

    // workspace layout (~20 MB)
    unsigned* ybf  = (unsigned*)d_ws;                   // N x 32 u32 (12.8 MB)
    float* stats   = (float*)(ybf + (size_t)N * 32);    // 3 x 256 floats
    int*   counts  = (int*)(stats + 3 * 256);           // N
    int*   cursor  = counts + N;                        // N
    int*   offsets = cursor + N;                        // N + 1
    int*   partials= offsets + N + 1;                   // ~128
    int*   eidx    = partials + 256;                    // E (6.4 MB)

    const int eblk   = (int)((E + 255) / 256);
    const int nscan  = (N + SCAN_CHUNK - 1) / SCAN_CHUNK;
    const int mblocks = (N + 31) / 32;
    const int nblocks = (N * DIM + 255) / 256;

    // ---- build CSR once (shared by all 3 layers) ----
    setup_kernel<<<512, 256, 0, stream>>>(counts, cursor, N, stats);
    hist_kernel<<<eblk, 256, 0, stream>>>(edges, E, counts);
    scan1_kernel<<<nscan, 256, 0, stream>>>(counts, N, partials);
    scan2_kernel<<<1, 64, 0, stream>>>(partials, nscan, offsets + N);
    scan3_kernel<<<nscan, 256, 0, stream>>>(counts, N, partials, offsets);
    fill_kernel<<<eblk, 256, 0, stream>>>(edges, E, offsets, cursor, eidx);

    for (int l = 0; l < 3; l++) {
        const float* h     = (l == 0) ? x : out_xs;
        const int h_stride = (l == 0) ? F_IN : XS_STRIDE;
        const int h_off    = (l == 0) ? 0 : (l - 1) * DIM;
        float* statsL = stats + l * 256;

        if (l == 0)
            proj_kernel<128><<<mblocks, 256, 0, stream>>>(h, h_stride, h_off, W[l][0], ybf, N);
        else
            proj_kernel<64><<<mblocks, 256, 0, stream>>>(h, h_stride, h_off, W[l][0], ybf, N);

        aggmlp_kernel<<<mblocks, 256, 0, stream>>>(ybf, offsets, eidx,
            W[l][1], W[l][2], W[l][3], out_xs, l * DIM, statsL, N);

        bnparam_kernel<<<1, 64, 0, stream>>>(statsL, W[l][4], W[l][5], statsL + 2 * DIM, N);

        norm_kernel<<<nblocks, 256, 0, stream>>>(out_xs, statsL + 2 * DIM, l * DIM, N);
    }

    pool_kernel<<<G, XS_STRIDE, 0, stream>>>(out_xs, batch, out_pool, N);
}

// Round 8
// 641.597 us; speedup vs baseline: 3.3121x; 1.6855x over previous
//
#include <hip/hip_runtime.h>

#define DIM 64
#define XS_STRIDE 192
#define BN_EPS 1e-5f
#define SCAN_CHUNK 1024

__device__ inline unsigned pack_bf16x2(float lo, float hi) {
    unsigned ulo = __float_as_uint(lo); ulo = (ulo + 0x7FFFu + ((ulo >> 16) & 1u)) >> 16;
    unsigned uhi = __float_as_uint(hi); uhi = (uhi + 0x7FFFu + ((uhi >> 16) & 1u)) >> 16;
    return ulo | (uhi << 16);
}
__device__ inline float2 unpack_bf16x2(unsigned v) {
    return make_float2(__uint_as_float(v << 16), __uint_as_float(v & 0xFFFF0000u));
}

// ---------------- setup: zero counts, cursor, stats, eidx pad ----------------
__global__ void setup_kernel(int* __restrict__ counts, int* __restrict__ cursor, int N,
                             float* __restrict__ stats, int* __restrict__ eidx_pad) {
    int gid = blockIdx.x * blockDim.x + threadIdx.x;
    int stride = gridDim.x * blockDim.x;
    for (int i = gid; i < N; i += stride) { counts[i] = 0; cursor[i] = 0; }
    if (gid < 3 * 256) stats[gid] = 0.f;
    if (blockIdx.x == 0 && threadIdx.x < 256) eidx_pad[threadIdx.x] = 0;
}

// ---------------- histogram of dst ----------------
__global__ void hist_kernel(const int* __restrict__ edges, long long E, int* __restrict__ counts) {
    long long e = (long long)blockIdx.x * 256 + threadIdx.x;
    if (e >= E) return;
    atomicAdd(&counts[edges[E + e]], 1);
}

// ---------------- scan step 1: per-chunk sums ----------------
__global__ void scan1_kernel(const int* __restrict__ counts, int N, int* __restrict__ partials) {
    __shared__ int red[256];
    int b = blockIdx.x, t = threadIdx.x;
    int base = b * SCAN_CHUNK;
    int s = 0;
    for (int i = t; i < SCAN_CHUNK; i += 256) {
        int idx = base + i;
        s += (idx < N) ? counts[idx] : 0;
    }
    red[t] = s; __syncthreads();
    for (int o = 128; o > 0; o >>= 1) { if (t < o) red[t] += red[t + o]; __syncthreads(); }
    if (t == 0) partials[b] = red[0];
}

// ---------------- scan step 2: exclusive scan of partials (tiny) ----------------
__global__ void scan2_kernel(int* __restrict__ partials, int nb, int* __restrict__ offsets_end) {
    if (threadIdx.x == 0) {
        int acc = 0;
        for (int i = 0; i < nb; i++) { int v = partials[i]; partials[i] = acc; acc += v; }
        *offsets_end = acc;   // offsets[N] = E
    }
}

// ---------------- scan step 3: chunk-local exclusive scan -> offsets ----------------
__global__ void scan3_kernel(const int* __restrict__ counts, int N,
                             const int* __restrict__ partials, int* __restrict__ offsets) {
    __shared__ int sbuf[2][256];
    int b = blockIdx.x, t = threadIdx.x;
    int base = b * SCAN_CHUNK;
    int v[4]; int s = 0;
    #pragma unroll
    for (int j = 0; j < 4; j++) {
        int idx = base + t * 4 + j;
        v[j] = (idx < N) ? counts[idx] : 0;
        s += v[j];
    }
    sbuf[0][t] = s; __syncthreads();
    int cur = 0;
    for (int o = 1; o < 256; o <<= 1) {
        int val = sbuf[cur][t];
        if (t >= o) val += sbuf[cur][t - o];
        sbuf[cur ^ 1][t] = val; __syncthreads(); cur ^= 1;
    }
    int excl = sbuf[cur][t] - s;
    int off = partials[b] + excl;
    #pragma unroll
    for (int j = 0; j < 4; j++) {
        int idx = base + t * 4 + j;
        if (idx < N) offsets[idx] = off;
        off += v[j];
    }
}

// ---------------- fill CSR edge index (src ids bucketed by dst) ----------------
__global__ void fill_kernel(const int* __restrict__ edges, long long E,
                            const int* __restrict__ offsets, int* __restrict__ cursor,
                            int* __restrict__ eidx) {
    long long e = (long long)blockIdx.x * 256 + threadIdx.x;
    if (e >= E) return;
    int src = edges[e];
    int dst = edges[E + e];
    int pos = atomicAdd(&cursor[dst], 1);
    eidx[offsets[dst] + pos] = src;
}

// ---- y = h @ w1, packed bf16x2: half-wave computes 2 cols x 4 rows ----
template<int DIN>
__global__ __launch_bounds__(256) void proj_kernel(
    const float* __restrict__ h, int h_stride, int h_off,
    const float* __restrict__ w1,
    unsigned* __restrict__ ybf, int N)
{
    constexpr int R = 32;
    __shared__ float w1s[DIN * DIM];
    __shared__ float hin[R][DIN];
    const int tid = threadIdx.x;
    const int row0 = blockIdx.x * R;

    for (int i = tid; i < DIN * DIM; i += 256) w1s[i] = w1[i];
    for (int i = tid; i < R * DIN; i += 256) {
        int r = i / DIN, k = i % DIN;
        int row = row0 + r;
        hin[r][k] = (row < N) ? h[(size_t)row * h_stride + h_off + k] : 0.f;
    }
    __syncthreads();

    const int hw = tid >> 5;       // half-wave 0..7 owns rows hw*4..hw*4+3
    const int hl = tid & 31;       // cols 2*hl, 2*hl+1
    float a0[4], a1[4];
    #pragma unroll
    for (int q = 0; q < 4; q++) { a0[q] = 0.f; a1[q] = 0.f; }
    for (int k = 0; k < DIN; k++) {
        float w0 = w1s[k * DIM + 2 * hl];
        float w1v = w1s[k * DIM + 2 * hl + 1];
        #pragma unroll
        for (int q = 0; q < 4; q++) {
            float hv = hin[hw * 4 + q][k];
            a0[q] += hv * w0; a1[q] += hv * w1v;
        }
    }
    #pragma unroll
    for (int q = 0; q < 4; q++) {
        int row = row0 + hw * 4 + q;
        if (row < N) ybf[(size_t)row * 32 + hl] = pack_bf16x2(a0[q], a1[q]);
    }
}

// ---- fused: half-wave walks 8 rows, 4-batched edges -> 32 gathers in flight ----
__global__ __launch_bounds__(256) void aggmlp_kernel(
    const unsigned* __restrict__ ybf,
    const int* __restrict__ offsets, const int* __restrict__ eidx,
    const float* __restrict__ b1,
    const float* __restrict__ w2, const float* __restrict__ b2,
    float* __restrict__ xs, int xs_off,
    float* __restrict__ stats, int N)
{
    constexpr int R = 64;
    __shared__ float w2s[DIM * DIM];     // 16KB
    __shared__ float zin[R][DIM];        // 16KB
    __shared__ float sred[2][DIM];
    const int tid  = threadIdx.x;
    const int row0 = blockIdx.x * R;
    const int hw = tid >> 5;             // half-wave 0..7 owns rows hw*8..hw*8+7
    const int hl = tid & 31;             // feature pair (2*hl, 2*hl+1)

    for (int i = tid; i < DIM * DIM; i += 256) w2s[i] = w2[i];
    if (tid < DIM) { sred[0][tid] = 0.f; sred[1][tid] = 0.f; }

    const float b1lo = b1[2 * hl], b1hi = b1[2 * hl + 1];
    int p0[8], pe[8];
    float ax[8], ay[8];
    #pragma unroll
    for (int q = 0; q < 8; q++) {
        int node = row0 + hw * 8 + q;
        if (node < N) {
            p0[q] = offsets[node];
            pe[q] = offsets[node + 1];
            float2 s = unpack_bf16x2(ybf[(size_t)node * 32 + hl]);
            ax[q] = s.x + b1lo; ay[q] = s.y + b1hi;
        } else { p0[q] = 0; pe[q] = 0; ax[q] = 0.f; ay[q] = 0.f; }
    }
    int steps = 0;
    #pragma unroll
    for (int q = 0; q < 8; q++) steps = max(steps, (pe[q] - p0[q] + 3) >> 2);

    for (int s = 0; s < steps; s++) {
        const int b = 4 * s;
        int e[32];
        #pragma unroll
        for (int q = 0; q < 8; q++) {
            #pragma unroll
            for (int j = 0; j < 4; j++)
                e[q * 4 + j] = eidx[p0[q] + b + j];   // unconditional; eidx padded
        }
        unsigned vv[32];
        #pragma unroll
        for (int t = 0; t < 32; t++)
            vv[t] = ybf[(size_t)e[t] * 32 + hl];
        #pragma unroll
        for (int q = 0; q < 8; q++) {
            #pragma unroll
            for (int j = 0; j < 4; j++) {
                float2 v = unpack_bf16x2(vv[q * 4 + j]);
                bool live = (p0[q] + b + j) < pe[q];
                ax[q] += live ? v.x : 0.f;
                ay[q] += live ? v.y : 0.f;
            }
        }
    }
    #pragma unroll
    for (int q = 0; q < 8; q++) {
        zin[hw * 8 + q][2 * hl]     = fmaxf(ax[q], 0.f);   // relu between linear layers
        zin[hw * 8 + q][2 * hl + 1] = fmaxf(ay[q], 0.f);
    }
    __syncthreads();

    // GEMM: relu(z) @ w2 + b2, register-tiled (16 rows/thread), lane = out col
    const int lane = tid & 63;
    const int wv_  = tid >> 6;
    float oacc[16];
    #pragma unroll
    for (int i = 0; i < 16; i++) oacc[i] = b2[lane];
    for (int k = 0; k < DIM; k++) {
        float w = w2s[k * DIM + lane];
        #pragma unroll
        for (int i = 0; i < 16; i++) oacc[i] += zin[wv_ + 4 * i][k] * w;
    }
    float s1 = 0.f, s2 = 0.f;
    #pragma unroll
    for (int i = 0; i < 16; i++) {
        int row = row0 + wv_ + 4 * i;
        if (row < N) {
            float v = fmaxf(oacc[i], 0.f);   // F.relu after conv
            xs[(size_t)row * XS_STRIDE + xs_off + lane] = v;
            s1 += v; s2 += v * v;
        }
    }
    atomicAdd(&sred[0][lane], s1);
    atomicAdd(&sred[1][lane], s2);
    __syncthreads();
    if (tid < DIM) {
        atomicAdd(&stats[tid], sred[0][tid]);
        atomicAdd(&stats[DIM + tid], sred[1][tid]);
    }
}

// ---------------- BN params: scale/shift from sum/sumsq ----------------
__global__ void bnparam_kernel(const float* __restrict__ stats,
                               const float* __restrict__ gamma, const float* __restrict__ beta,
                               float* __restrict__ sc, int N) {
    int c = threadIdx.x;  // 64 threads
    float inv_n = 1.0f / (float)N;
    float mean = stats[c] * inv_n;
    float var  = stats[DIM + c] * inv_n - mean * mean;
    float scale = gamma[c] * rsqrtf(var + BN_EPS);
    sc[c] = scale;
    sc[DIM + c] = beta[c] - mean * scale;
}

// ---------------- in-place BN normalize of xs columns ----------------
__global__ void norm_kernel(float* __restrict__ xs, const float* __restrict__ sc,
                            int xs_off, int N) {
    int gid = blockIdx.x * blockDim.x + threadIdx.x;
    if (gid >= N * DIM) return;
    int n = gid >> 6, c = gid & 63;
    size_t p = (size_t)n * XS_STRIDE + xs_off + c;
    xs[p] = xs[p] * sc[c] + sc[DIM + c];
}

// ---------------- per-graph pooling (batch sorted -> binary search) ----------------
__global__ void pool_kernel(const float* __restrict__ xs, const int* __restrict__ batch,
                            float* __restrict__ pool, int N) {
    int g = blockIdx.x;
    int tid = threadIdx.x;  // 192 threads
    int lo = 0, hi = N;
    while (lo < hi) { int mid = (lo + hi) >> 1; if (batch[mid] < g) lo = mid + 1; else hi = mid; }
    int start = lo;
    hi = N;
    while (lo < hi) { int mid = (lo + hi) >> 1; if (batch[mid] < g + 1) lo = mid + 1; else hi = mid; }
    int end = lo;
    float s = 0.f;
    for (int n = start; n < end; n++) s += xs[(size_t)n * XS_STRIDE + tid];
    pool[(size_t)g * XS_STRIDE + tid] = s;
}

extern "C" void kernel_launch(void* const* d_in, const int* in_sizes, int n_in,
                              void* d_out, int out_size, void* d_ws, size_t ws_size,
                              hipStream_t stream) {
    const float* x     = (const float*)d_in[0];
    const int*   edges = (const int*)d_in[1];   // int32 (harness converts integer inputs)
    const int*   batch = (const int*)d_in[2];   // int32

    const int  N    = in_sizes[2];
    const long long E = in_sizes[1] / 2;
    const int  F_IN = in_sizes[0] / N;              // 128
    const int  G    = out_size / XS_STRIDE - N;     // 1000

    const float* W[3][6];
    for (int l = 0; l < 3; l++)
        for (int p = 0; p < 6; p++)
            W[l][p] = (const float*)d_in[4 + l * 6 + p];

    float* out_pool = (float*)d_out;                        // G x 192
    float* out_xs   = out_pool + (size_t)G * XS_STRIDE;     // N x 192

    // workspace layout (~20 MB)
    unsigned* ybf  = (unsigned*)d_ws;                   // N x 32 u32 (12.8 MB)
    float* stats   = (float*)(ybf + (size_t)N * 32);    // 3 x 256 floats
    int*   counts  = (int*)(stats + 3 * 256);           // N
    int*   cursor  = counts + N;                        // N
    int*   offsets = cursor + N;                        // N + 1
    int*   partials= offsets + N + 1;                   // ~128
    int*   eidx    = partials + 256;                    // E + 256 pad (6.4 MB)

    const int eblk   = (int)((E + 255) / 256);
    const int nscan  = (N + SCAN_CHUNK - 1) / SCAN_CHUNK;
    const int pblocks = (N + 31) / 32;
    const int ablocks = (N + 63) / 64;
    const int nblocks = (N * DIM + 255) / 256;

    // ---- build CSR once (shared by all 3 layers) ----
    setup_kernel<<<512, 256, 0, stream>>>(counts, cursor, N, stats, eidx + E);
    hist_kernel<<<eblk, 256, 0, stream>>>(edges, E, counts);
    scan1_kernel<<<nscan, 256, 0, stream>>>(counts, N, partials);
    scan2_kernel<<<1, 64, 0, stream>>>(partials, nscan, offsets + N);
    scan3_kernel<<<nscan, 256, 0, stream>>>(counts, N, partials, offsets);
    fill_kernel<<<eblk, 256, 0, stream>>>(edges, E, offsets, cursor, eidx);

    for (int l = 0; l < 3; l++) {
        const float* h     = (l == 0) ? x : out_xs;
        const int h_stride = (l == 0) ? F_IN : XS_STRIDE;
        const int h_off    = (l == 0) ? 0 : (l - 1) * DIM;
        float* statsL = stats + l * 256;

        if (l == 0)
            proj_kernel<128><<<pblocks, 256, 0, stream>>>(h, h_stride, h_off, W[l][0], ybf, N);
        else
            proj_kernel<64><<<pblocks, 256, 0, stream>>>(h, h_stride, h_off, W[l][0], ybf, N);

        aggmlp_kernel<<<ablocks, 256, 0, stream>>>(ybf, offsets, eidx,
            W[l][1], W[l][2], W[l][3], out_xs, l * DIM, statsL, N);

        bnparam_kernel<<<1, 64, 0, stream>>>(statsL, W[l][4], W[l][5], statsL + 2 * DIM, N);

        norm_kernel<<<nblocks, 256, 0, stream>>>(out_xs, statsL + 2 * DIM, l * DIM, N);
    }

    pool_kernel<<<G, XS_STRIDE, 0, stream>>>(out_xs, batch, out_pool, N);
}

// Round 9
// 602.673 us; speedup vs baseline: 3.5260x; 1.0646x over previous
//
#include <hip/hip_runtime.h>

#define DIM 64
#define XS_STRIDE 192
#define BN_EPS 1e-5f
#define SCAN_CHUNK 1024

__device__ inline unsigned pack_bf16x2(float lo, float hi) {
    unsigned ulo = __float_as_uint(lo); ulo = (ulo + 0x7FFFu + ((ulo >> 16) & 1u)) >> 16;
    unsigned uhi = __float_as_uint(hi); uhi = (uhi + 0x7FFFu + ((uhi >> 16) & 1u)) >> 16;
    return ulo | (uhi << 16);
}
__device__ inline float2 unpack_bf16x2(unsigned v) {
    return make_float2(__uint_as_float(v << 16), __uint_as_float(v & 0xFFFF0000u));
}

// ---------------- setup: zero counts, stats, eidx pad ----------------
__global__ void setup_kernel(int* __restrict__ counts, int N,
                             float* __restrict__ stats, int* __restrict__ eidx_pad) {
    int gid = blockIdx.x * blockDim.x + threadIdx.x;
    int stride = gridDim.x * blockDim.x;
    for (int i = gid; i < N; i += stride) counts[i] = 0;
    if (gid < 3 * 256) stats[gid] = 0.f;
    if (blockIdx.x == 0 && threadIdx.x < 256) eidx_pad[threadIdx.x] = 0;
}

// ---------------- histogram of dst ----------------
__global__ void hist_kernel(const int* __restrict__ edges, long long E, int* __restrict__ counts) {
    long long e = (long long)blockIdx.x * 256 + threadIdx.x;
    if (e >= E) return;
    atomicAdd(&counts[edges[E + e]], 1);
}

// ---------------- scan step 1: per-chunk sums ----------------
__global__ void scan1_kernel(const int* __restrict__ counts, int N, int* __restrict__ partials) {
    __shared__ int red[256];
    int b = blockIdx.x, t = threadIdx.x;
    int base = b * SCAN_CHUNK;
    int s = 0;
    for (int i = t; i < SCAN_CHUNK; i += 256) {
        int idx = base + i;
        s += (idx < N) ? counts[idx] : 0;
    }
    red[t] = s; __syncthreads();
    for (int o = 128; o > 0; o >>= 1) { if (t < o) red[t] += red[t + o]; __syncthreads(); }
    if (t == 0) partials[b] = red[0];
}

// ---------------- scan step 2: exclusive scan of partials (tiny) ----------------
__global__ void scan2_kernel(int* __restrict__ partials, int nb, int* __restrict__ offsets_end) {
    if (threadIdx.x == 0) {
        int acc = 0;
        for (int i = 0; i < nb; i++) { int v = partials[i]; partials[i] = acc; acc += v; }
        *offsets_end = acc;   // offsets[N] = E
    }
}

// ---------------- scan step 3: chunk-local exclusive scan -> offsets ----------------
__global__ void scan3_kernel(const int* __restrict__ counts, int N,
                             const int* __restrict__ partials, int* __restrict__ offsets) {
    __shared__ int sbuf[2][256];
    int b = blockIdx.x, t = threadIdx.x;
    int base = b * SCAN_CHUNK;
    int v[4]; int s = 0;
    #pragma unroll
    for (int j = 0; j < 4; j++) {
        int idx = base + t * 4 + j;
        v[j] = (idx < N) ? counts[idx] : 0;
        s += v[j];
    }
    sbuf[0][t] = s; __syncthreads();
    int cur = 0;
    for (int o = 1; o < 256; o <<= 1) {
        int val = sbuf[cur][t];
        if (t >= o) val += sbuf[cur][t - o];
        sbuf[cur ^ 1][t] = val; __syncthreads(); cur ^= 1;
    }
    int excl = sbuf[cur][t] - s;
    int off = partials[b] + excl;
    #pragma unroll
    for (int j = 0; j < 4; j++) {
        int idx = base + t * 4 + j;
        if (idx < N) offsets[idx] = off;
        off += v[j];
    }
}

// ---- fill CSR: counts doubles as cursor (decrement); NT store avoids L2 false sharing ----
__global__ void fill_kernel(const int* __restrict__ edges, long long E,
                            const int* __restrict__ offsets, int* __restrict__ counts,
                            int* __restrict__ eidx) {
    long long e = (long long)blockIdx.x * 256 + threadIdx.x;
    if (e >= E) return;
    int src = edges[e];
    int dst = edges[E + e];
    int pos = atomicSub(&counts[dst], 1) - 1;
    __builtin_nontemporal_store(src, &eidx[offsets[dst] + pos]);
}

// ---- y = h @ w1 (bf16x2 packed); optional fused BN of input (write normalized back) ----
template<int DIN, bool FUSE>
__global__ __launch_bounds__(256) void proj_kernel(
    const float* __restrict__ h, int h_stride, int h_off,
    float* __restrict__ h_back,            // == h when FUSE (in-place normalize)
    const float* __restrict__ w1,
    const float* __restrict__ scsh,        // sc[64], sh[64] (for FUSE)
    unsigned* __restrict__ ybf, int N)
{
    constexpr int R = 32;
    __shared__ float w1s[DIN * DIM];
    __shared__ float hin[R][DIN];
    const int tid = threadIdx.x;
    const int row0 = blockIdx.x * R;

    for (int i = tid; i < DIN * DIM; i += 256) w1s[i] = w1[i];
    for (int i = tid; i < R * DIN; i += 256) {
        int r = i / DIN, k = i % DIN;
        int row = row0 + r;
        float hv = 0.f;
        if (row < N) {
            hv = h[(size_t)row * h_stride + h_off + k];
            if (FUSE) {
                hv = hv * scsh[k] + scsh[DIM + k];
                h_back[(size_t)row * h_stride + h_off + k] = hv;   // write normalized xs
            }
        }
        hin[r][k] = hv;
    }
    __syncthreads();

    const int hw = tid >> 5;       // half-wave 0..7 owns rows hw*4..hw*4+3
    const int hl = tid & 31;       // cols 2*hl, 2*hl+1
    float a0[4], a1[4];
    #pragma unroll
    for (int q = 0; q < 4; q++) { a0[q] = 0.f; a1[q] = 0.f; }
    for (int k = 0; k < DIN; k++) {
        float w0 = w1s[k * DIM + 2 * hl];
        float w1v = w1s[k * DIM + 2 * hl + 1];
        #pragma unroll
        for (int q = 0; q < 4; q++) {
            float hv = hin[hw * 4 + q][k];
            a0[q] += hv * w0; a1[q] += hv * w1v;
        }
    }
    #pragma unroll
    for (int q = 0; q < 4; q++) {
        int row = row0 + hw * 4 + q;
        if (row < N) ybf[(size_t)row * 32 + hl] = pack_bf16x2(a0[q], a1[q]);
    }
}

// ---- fused: half-wave walks 8 rows, 4-batched edges -> 32 gathers in flight ----
__global__ __launch_bounds__(256) void aggmlp_kernel(
    const unsigned* __restrict__ ybf,
    const int* __restrict__ offsets, const int* __restrict__ eidx,
    const float* __restrict__ b1,
    const float* __restrict__ w2, const float* __restrict__ b2,
    float* __restrict__ xs, int xs_off,
    float* __restrict__ stats, int N)
{
    constexpr int R = 64;
    __shared__ float zin[R][DIM];        // 16KB
    __shared__ float sred[2][DIM];
    const int tid  = threadIdx.x;
    const int row0 = blockIdx.x * R;
    const int hw = tid >> 5;             // half-wave 0..7 owns rows hw*8..hw*8+7
    const int hl = tid & 31;             // feature pair (2*hl, 2*hl+1)

    if (tid < DIM) { sred[0][tid] = 0.f; sred[1][tid] = 0.f; }

    const float b1lo = b1[2 * hl], b1hi = b1[2 * hl + 1];
    int p0[8], pe[8];
    float ax[8], ay[8];
    #pragma unroll
    for (int q = 0; q < 8; q++) {
        int node = row0 + hw * 8 + q;
        if (node < N) {
            p0[q] = offsets[node];
            pe[q] = offsets[node + 1];
            float2 s = unpack_bf16x2(ybf[(size_t)node * 32 + hl]);
            ax[q] = s.x + b1lo; ay[q] = s.y + b1hi;
        } else { p0[q] = 0; pe[q] = 0; ax[q] = 0.f; ay[q] = 0.f; }
    }
    int steps = 0;
    #pragma unroll
    for (int q = 0; q < 8; q++) steps = max(steps, (pe[q] - p0[q] + 3) >> 2);

    for (int s = 0; s < steps; s++) {
        const int b = 4 * s;
        int e[32];
        #pragma unroll
        for (int q = 0; q < 8; q++) {
            #pragma unroll
            for (int j = 0; j < 4; j++)
                e[q * 4 + j] = eidx[p0[q] + b + j];   // unconditional; eidx padded
        }
        unsigned vv[32];
        #pragma unroll
        for (int t = 0; t < 32; t++)
            vv[t] = ybf[(size_t)e[t] * 32 + hl];
        #pragma unroll
        for (int q = 0; q < 8; q++) {
            #pragma unroll
            for (int j = 0; j < 4; j++) {
                float2 v = unpack_bf16x2(vv[q * 4 + j]);
                bool live = (p0[q] + b + j) < pe[q];
                ax[q] += live ? v.x : 0.f;
                ay[q] += live ? v.y : 0.f;
            }
        }
    }
    #pragma unroll
    for (int q = 0; q < 8; q++) {
        zin[hw * 8 + q][2 * hl]     = fmaxf(ax[q], 0.f);   // relu between linear layers
        zin[hw * 8 + q][2 * hl + 1] = fmaxf(ay[q], 0.f);
    }
    __syncthreads();

    // GEMM: relu(z) @ w2 + b2, register-tiled (16 rows/thread); w2 from global (L1-hot)
    const int lane = tid & 63;
    const int wv_  = tid >> 6;
    float oacc[16];
    #pragma unroll
    for (int i = 0; i < 16; i++) oacc[i] = b2[lane];
    for (int k = 0; k < DIM; k++) {
        float w = w2[k * DIM + lane];
        #pragma unroll
        for (int i = 0; i < 16; i++) oacc[i] += zin[wv_ + 4 * i][k] * w;
    }
    float s1 = 0.f, s2 = 0.f;
    #pragma unroll
    for (int i = 0; i < 16; i++) {
        int row = row0 + wv_ + 4 * i;
        if (row < N) {
            float v = fmaxf(oacc[i], 0.f);   // F.relu after conv
            xs[(size_t)row * XS_STRIDE + xs_off + lane] = v;
            s1 += v; s2 += v * v;
        }
    }
    atomicAdd(&sred[0][lane], s1);
    atomicAdd(&sred[1][lane], s2);
    __syncthreads();
    if (tid < DIM) {
        atomicAdd(&stats[tid], sred[0][tid]);
        atomicAdd(&stats[DIM + tid], sred[1][tid]);
    }
}

// ---------------- BN params: scale/shift from sum/sumsq ----------------
__global__ void bnparam_kernel(const float* __restrict__ stats,
                               const float* __restrict__ gamma, const float* __restrict__ beta,
                               float* __restrict__ sc, int N) {
    int c = threadIdx.x;  // 64 threads
    float inv_n = 1.0f / (float)N;
    float mean = stats[c] * inv_n;
    float var  = stats[DIM + c] * inv_n - mean * mean;
    float scale = gamma[c] * rsqrtf(var + BN_EPS);
    sc[c] = scale;
    sc[DIM + c] = beta[c] - mean * scale;
}

// ---- per-graph pooling; also applies layer-2 BN inline (cols 128..191) + write-back ----
__global__ void pool_kernel(float* __restrict__ xs, const int* __restrict__ batch,
                            float* __restrict__ pool, const float* __restrict__ scsh2, int N) {
    int g = blockIdx.x;
    int tid = threadIdx.x;  // 192 threads
    int lo = 0, hi = N;
    while (lo < hi) { int mid = (lo + hi) >> 1; if (batch[mid] < g) lo = mid + 1; else hi = mid; }
    int start = lo;
    hi = N;
    while (lo < hi) { int mid = (lo + hi) >> 1; if (batch[mid] < g + 1) lo = mid + 1; else hi = mid; }
    int end = lo;
    float s = 0.f;
    if (tid < 2 * DIM) {
        for (int n = start; n < end; n++) s += xs[(size_t)n * XS_STRIDE + tid];
    } else {
        const float sc = scsh2[tid - 2 * DIM];
        const float sh = scsh2[DIM + tid - 2 * DIM];
        for (int n = start; n < end; n++) {
            size_t p = (size_t)n * XS_STRIDE + tid;
            float v = xs[p] * sc + sh;     // layer-2 BN applied here
            xs[p] = v;
            s += v;
        }
    }
    pool[(size_t)g * XS_STRIDE + tid] = s;
}

extern "C" void kernel_launch(void* const* d_in, const int* in_sizes, int n_in,
                              void* d_out, int out_size, void* d_ws, size_t ws_size,
                              hipStream_t stream) {
    const float* x     = (const float*)d_in[0];
    const int*   edges = (const int*)d_in[1];   // int32 (harness converts integer inputs)
    const int*   batch = (const int*)d_in[2];   // int32

    const int  N    = in_sizes[2];
    const long long E = in_sizes[1] / 2;
    const int  F_IN = in_sizes[0] / N;              // 128
    const int  G    = out_size / XS_STRIDE - N;     // 1000

    const float* W[3][6];
    for (int l = 0; l < 3; l++)
        for (int p = 0; p < 6; p++)
            W[l][p] = (const float*)d_in[4 + l * 6 + p];

    float* out_pool = (float*)d_out;                        // G x 192
    float* out_xs   = out_pool + (size_t)G * XS_STRIDE;     // N x 192

    // workspace layout (~20 MB)
    unsigned* ybf  = (unsigned*)d_ws;                   // N x 32 u32 (12.8 MB)
    float* stats   = (float*)(ybf + (size_t)N * 32);    // 3 x 256 floats
    int*   counts  = (int*)(stats + 3 * 256);           // N (doubles as fill cursor)
    int*   offsets = counts + N;                        // N + 1
    int*   partials= offsets + N + 1;                   // ~256
    int*   eidx    = partials + 256;                    // E + 256 pad (6.4 MB)

    const int eblk   = (int)((E + 255) / 256);
    const int nscan  = (N + SCAN_CHUNK - 1) / SCAN_CHUNK;
    const int pblocks = (N + 31) / 32;
    const int ablocks = (N + 63) / 64;

    // ---- build CSR once (shared by all 3 layers) ----
    setup_kernel<<<512, 256, 0, stream>>>(counts, N, stats, eidx + E);
    hist_kernel<<<eblk, 256, 0, stream>>>(edges, E, counts);
    scan1_kernel<<<nscan, 256, 0, stream>>>(counts, N, partials);
    scan2_kernel<<<1, 64, 0, stream>>>(partials, nscan, offsets + N);
    scan3_kernel<<<nscan, 256, 0, stream>>>(counts, N, partials, offsets);
    fill_kernel<<<eblk, 256, 0, stream>>>(edges, E, offsets, counts, eidx);

    for (int l = 0; l < 3; l++) {
        const int h_off = (l == 0) ? 0 : (l - 1) * DIM;
        float* statsL = stats + l * 256;

        if (l == 0)
            proj_kernel<128, false><<<pblocks, 256, 0, stream>>>(
                x, F_IN, 0, nullptr, W[l][0], nullptr, ybf, N);
        else
            proj_kernel<64, true><<<pblocks, 256, 0, stream>>>(
                out_xs, XS_STRIDE, h_off, out_xs,
                W[l][0], stats + (l - 1) * 256 + 2 * DIM, ybf, N);

        aggmlp_kernel<<<ablocks, 256, 0, stream>>>(ybf, offsets, eidx,
            W[l][1], W[l][2], W[l][3], out_xs, l * DIM, statsL, N);

        bnparam_kernel<<<1, 64, 0, stream>>>(statsL, W[l][4], W[l][5], statsL + 2 * DIM, N);
    }

    pool_kernel<<<G, XS_STRIDE, 0, stream>>>(out_xs, batch, out_pool,
                                             stats + 2 * 256 + 2 * DIM, N);
}

// Round 10
// 499.442 us; speedup vs baseline: 4.2548x; 1.2067x over previous
//
#include <hip/hip_runtime.h>

#define DIM 64
#define XS_STRIDE 192
#define BN_EPS 1e-5f
#define B_MAX 512          // max dst buckets (N up to 131072 at W=256)
#define P4_CAP 6144        // LDS staging cap per bucket (mean 4092, 32 sigma)
#define CSR_CHUNK 16384    // edges per partition block

__device__ inline unsigned pack_bf16x2(float lo, float hi) {
    unsigned ulo = __float_as_uint(lo); ulo = (ulo + 0x7FFFu + ((ulo >> 16) & 1u)) >> 16;
    unsigned uhi = __float_as_uint(hi); uhi = (uhi + 0x7FFFu + ((uhi >> 16) & 1u)) >> 16;
    return ulo | (uhi << 16);
}
__device__ inline float2 unpack_bf16x2(unsigned v) {
    return make_float2(__uint_as_float(v << 16), __uint_as_float(v & 0xFFFF0000u));
}

// ---------------- setup: zero stats, eidx pad, offsets[N] ----------------
__global__ void setup_kernel(float* __restrict__ stats, int* __restrict__ eidx_pad,
                             int* __restrict__ offsetN, int E) {
    int t = threadIdx.x;
    if (t < 3 * 256) stats[t] = 0.f;
    if (t < 256) eidx_pad[t] = 0;
    if (t == 0) *offsetN = E;
}

// ---------------- P1: per-chunk bucket histogram ----------------
__global__ __launch_bounds__(256) void p1_hist(const int* __restrict__ dsts, long long E,
                                               int NB1, int B, int* __restrict__ bh) {
    __shared__ int hist[B_MAX];
    const int i = blockIdx.x, t = threadIdx.x;
    for (int b = t; b < B; b += 256) hist[b] = 0;
    __syncthreads();
    long long s0 = (long long)i * CSR_CHUNK;
    long long s1 = s0 + CSR_CHUNK; if (s1 > E) s1 = E;
    for (long long e = s0 + t; e < s1; e += 256)
        atomicAdd(&hist[dsts[e] >> 8], 1);
    __syncthreads();
    for (int b = t; b < B; b += 256) bh[b * NB1 + i] = hist[b];
}

// ---------------- P2: one-block exclusive scan of bh[B*NB1] ----------------
__global__ __launch_bounds__(1024) void p2_scan(int* __restrict__ bh, int total_n) {
    __shared__ int sbuf[2][1024];
    const int t = threadIdx.x;
    const int seg = (total_n + 1023) / 1024;
    int s0 = t * seg, s1 = s0 + seg; if (s1 > total_n) s1 = total_n;
    int s = 0;
    for (int i = s0; i < s1; i++) s += bh[i];
    sbuf[0][t] = s; __syncthreads();
    int c = 0;
    for (int o = 1; o < 1024; o <<= 1) {
        int val = sbuf[c][t];
        if (t >= o) val += sbuf[c][t - o];
        sbuf[c ^ 1][t] = val; __syncthreads(); c ^= 1;
    }
    int run = sbuf[c][t] - s;       // exclusive base for this thread's segment
    for (int i = s0; i < s1; i++) { int v = bh[i]; bh[i] = run; run += v; }
}

// ---------------- P3: partition edges into bucket runs (block-private, dense) ----------------
__global__ __launch_bounds__(256) void p3_part(const int* __restrict__ edges, long long E,
                                               int NB1, int B, const int* __restrict__ bh,
                                               unsigned* __restrict__ ebuf) {
    __shared__ int cur[B_MAX];
    const int i = blockIdx.x, t = threadIdx.x;
    for (int b = t; b < B; b += 256) cur[b] = bh[b * NB1 + i];
    __syncthreads();
    long long s0 = (long long)i * CSR_CHUNK;
    long long s1 = s0 + CSR_CHUNK; if (s1 > E) s1 = E;
    for (long long e = s0 + t; e < s1; e += 256) {
        int src = edges[e];
        int dst = edges[E + e];
        int b = dst >> 8;
        int pos = atomicAdd(&cur[b], 1);
        ebuf[pos] = (unsigned)src | ((unsigned)(dst & 255) << 24);
    }
}

// ---------------- P4: per-bucket local CSR (LDS-staged, dense writes) ----------------
__global__ __launch_bounds__(256) void p4_build(const unsigned* __restrict__ ebuf, long long E,
                                                int NB1, int B, const int* __restrict__ bh,
                                                int* __restrict__ offsets, int* __restrict__ eidx,
                                                int N) {
    __shared__ unsigned lbuf[P4_CAP];
    __shared__ int hist[256];
    __shared__ int sbuf[2][256];
    __shared__ int cur[256];
    const int b = blockIdx.x, t = threadIdx.x;
    const int s = bh[b * NB1];
    const int e = (b + 1 < B) ? bh[(b + 1) * NB1] : (int)E;
    const int sz = e - s;
    const bool inl = (sz <= P4_CAP);
    if (inl) for (int k = t; k < sz; k += 256) lbuf[k] = ebuf[s + k];
    hist[t] = 0;
    __syncthreads();
    for (int k = t; k < sz; k += 256) {
        unsigned v = inl ? lbuf[k] : ebuf[s + k];
        atomicAdd(&hist[v >> 24], 1);
    }
    __syncthreads();
    int h = hist[t];
    sbuf[0][t] = h; __syncthreads();
    int c = 0;
    for (int o = 1; o < 256; o <<= 1) {
        int val = sbuf[c][t];
        if (t >= o) val += sbuf[c][t - o];
        sbuf[c ^ 1][t] = val; __syncthreads(); c ^= 1;
    }
    int excl = sbuf[c][t] - h;
    int node = b * 256 + t;
    if (node < N) offsets[node] = s + excl;
    cur[t] = excl;
    __syncthreads();
    for (int k = t; k < sz; k += 256) {
        unsigned v = inl ? lbuf[k] : ebuf[s + k];
        int dl = v >> 24;
        int pos = atomicAdd(&cur[dl], 1);
        eidx[s + pos] = (int)(v & 0xFFFFFFu);
    }
}

// ---- y = h @ w1 (bf16x2 packed); optional fused BN of input (write normalized back) ----
template<int DIN, bool FUSE>
__global__ __launch_bounds__(256) void proj_kernel(
    const float* __restrict__ h, int h_stride, int h_off,
    float* __restrict__ h_back,            // == h when FUSE (in-place normalize)
    const float* __restrict__ w1,
    const float* __restrict__ scsh,        // sc[64], sh[64] (for FUSE)
    unsigned* __restrict__ ybf, int N)
{
    constexpr int R = 32;
    __shared__ float w1s[DIN * DIM];
    __shared__ float hin[R][DIN];
    const int tid = threadIdx.x;
    const int row0 = blockIdx.x * R;

    for (int i = tid; i < DIN * DIM / 4; i += 256)
        *(float4*)&w1s[i * 4] = *(const float4*)&w1[i * 4];
    for (int i = tid; i < R * DIN / 4; i += 256) {
        int r = i / (DIN / 4), k4 = (i % (DIN / 4)) * 4;
        int row = row0 + r;
        float4 hv = make_float4(0.f, 0.f, 0.f, 0.f);
        if (row < N) {
            hv = *(const float4*)&h[(size_t)row * h_stride + h_off + k4];
            if (FUSE) {
                hv.x = hv.x * scsh[k4 + 0] + scsh[DIM + k4 + 0];
                hv.y = hv.y * scsh[k4 + 1] + scsh[DIM + k4 + 1];
                hv.z = hv.z * scsh[k4 + 2] + scsh[DIM + k4 + 2];
                hv.w = hv.w * scsh[k4 + 3] + scsh[DIM + k4 + 3];
                *(float4*)&h_back[(size_t)row * h_stride + h_off + k4] = hv;
            }
        }
        *(float4*)&hin[r][k4] = hv;
    }
    __syncthreads();

    const int hw = tid >> 5;       // half-wave 0..7 owns rows hw*4..hw*4+3
    const int hl = tid & 31;       // cols 2*hl, 2*hl+1
    float a0[4], a1[4];
    #pragma unroll
    for (int q = 0; q < 4; q++) { a0[q] = 0.f; a1[q] = 0.f; }
    for (int k = 0; k < DIN; k++) {
        float w0 = w1s[k * DIM + 2 * hl];
        float w1v = w1s[k * DIM + 2 * hl + 1];
        #pragma unroll
        for (int q = 0; q < 4; q++) {
            float hv = hin[hw * 4 + q][k];
            a0[q] += hv * w0; a1[q] += hv * w1v;
        }
    }
    #pragma unroll
    for (int q = 0; q < 4; q++) {
        int row = row0 + hw * 4 + q;
        if (row < N) ybf[(size_t)row * 32 + hl] = pack_bf16x2(a0[q], a1[q]);
    }
}

// ---- fused: half-wave walks 8 rows, 4-batched edges -> 32 gathers in flight ----
__global__ __launch_bounds__(256) void aggmlp_kernel(
    const unsigned* __restrict__ ybf,
    const int* __restrict__ offsets, const int* __restrict__ eidx,
    const float* __restrict__ b1,
    const float* __restrict__ w2, const float* __restrict__ b2,
    float* __restrict__ xs, int xs_off,
    float* __restrict__ stats, int N)
{
    constexpr int R = 64;
    __shared__ float zin[R][DIM];        // 16KB
    __shared__ float sred[2][DIM];
    const int tid  = threadIdx.x;
    const int row0 = blockIdx.x * R;
    const int hw = tid >> 5;             // half-wave 0..7 owns rows hw*8..hw*8+7
    const int hl = tid & 31;             // feature pair (2*hl, 2*hl+1)

    if (tid < DIM) { sred[0][tid] = 0.f; sred[1][tid] = 0.f; }

    const float b1lo = b1[2 * hl], b1hi = b1[2 * hl + 1];
    int p0[8], pe[8];
    float ax[8], ay[8];
    #pragma unroll
    for (int q = 0; q < 8; q++) {
        int node = row0 + hw * 8 + q;
        if (node < N) {
            p0[q] = offsets[node];
            pe[q] = offsets[node + 1];
            float2 s = unpack_bf16x2(ybf[(size_t)node * 32 + hl]);
            ax[q] = s.x + b1lo; ay[q] = s.y + b1hi;
        } else { p0[q] = 0; pe[q] = 0; ax[q] = 0.f; ay[q] = 0.f; }
    }
    int steps = 0;
    #pragma unroll
    for (int q = 0; q < 8; q++) steps = max(steps, (pe[q] - p0[q] + 3) >> 2);

    for (int s = 0; s < steps; s++) {
        const int b = 4 * s;
        int e[32];
        #pragma unroll
        for (int q = 0; q < 8; q++) {
            #pragma unroll
            for (int j = 0; j < 4; j++)
                e[q * 4 + j] = eidx[p0[q] + b + j];   // unconditional; eidx padded
        }
        unsigned vv[32];
        #pragma unroll
        for (int t = 0; t < 32; t++)
            vv[t] = ybf[(size_t)e[t] * 32 + hl];
        #pragma unroll
        for (int q = 0; q < 8; q++) {
            #pragma unroll
            for (int j = 0; j < 4; j++) {
                float2 v = unpack_bf16x2(vv[q * 4 + j]);
                bool live = (p0[q] + b + j) < pe[q];
                ax[q] += live ? v.x : 0.f;
                ay[q] += live ? v.y : 0.f;
            }
        }
    }
    #pragma unroll
    for (int q = 0; q < 8; q++) {
        zin[hw * 8 + q][2 * hl]     = fmaxf(ax[q], 0.f);   // relu between linear layers
        zin[hw * 8 + q][2 * hl + 1] = fmaxf(ay[q], 0.f);
    }
    __syncthreads();

    // GEMM: relu(z) @ w2 + b2, register-tiled (16 rows/thread); w2 from global (L1-hot)
    const int lane = tid & 63;
    const int wv_  = tid >> 6;
    float oacc[16];
    #pragma unroll
    for (int i = 0; i < 16; i++) oacc[i] = b2[lane];
    for (int k = 0; k < DIM; k++) {
        float w = w2[k * DIM + lane];
        #pragma unroll
        for (int i = 0; i < 16; i++) oacc[i] += zin[wv_ + 4 * i][k] * w;
    }
    float s1 = 0.f, s2 = 0.f;
    #pragma unroll
    for (int i = 0; i < 16; i++) {
        int row = row0 + wv_ + 4 * i;
        if (row < N) {
            float v = fmaxf(oacc[i], 0.f);   // F.relu after conv
            xs[(size_t)row * XS_STRIDE + xs_off + lane] = v;
            s1 += v; s2 += v * v;
        }
    }
    atomicAdd(&sred[0][lane], s1);
    atomicAdd(&sred[1][lane], s2);
    __syncthreads();
    if (tid < DIM) {
        atomicAdd(&stats[tid], sred[0][tid]);
        atomicAdd(&stats[DIM + tid], sred[1][tid]);
    }
}

// ---------------- BN params: scale/shift from sum/sumsq ----------------
__global__ void bnparam_kernel(const float* __restrict__ stats,
                               const float* __restrict__ gamma, const float* __restrict__ beta,
                               float* __restrict__ sc, int N) {
    int c = threadIdx.x;  // 64 threads
    float inv_n = 1.0f / (float)N;
    float mean = stats[c] * inv_n;
    float var  = stats[DIM + c] * inv_n - mean * mean;
    float scale = gamma[c] * rsqrtf(var + BN_EPS);
    sc[c] = scale;
    sc[DIM + c] = beta[c] - mean * scale;
}

// ---- per-graph pooling; also applies layer-2 BN inline (cols 128..191) + write-back ----
__global__ void pool_kernel(float* __restrict__ xs, const int* __restrict__ batch,
                            float* __restrict__ pool, const float* __restrict__ scsh2, int N) {
    int g = blockIdx.x;
    int tid = threadIdx.x;  // 192 threads
    int lo = 0, hi = N;
    while (lo < hi) { int mid = (lo + hi) >> 1; if (batch[mid] < g) lo = mid + 1; else hi = mid; }
    int start = lo;
    hi = N;
    while (lo < hi) { int mid = (lo + hi) >> 1; if (batch[mid] < g + 1) lo = mid + 1; else hi = mid; }
    int end = lo;
    float s = 0.f;
    if (tid < 2 * DIM) {
        for (int n = start; n < end; n++) s += xs[(size_t)n * XS_STRIDE + tid];
    } else {
        const float sc = scsh2[tid - 2 * DIM];
        const float sh = scsh2[DIM + tid - 2 * DIM];
        for (int n = start; n < end; n++) {
            size_t p = (size_t)n * XS_STRIDE + tid;
            float v = xs[p] * sc + sh;     // layer-2 BN applied here
            xs[p] = v;
            s += v;
        }
    }
    pool[(size_t)g * XS_STRIDE + tid] = s;
}

extern "C" void kernel_launch(void* const* d_in, const int* in_sizes, int n_in,
                              void* d_out, int out_size, void* d_ws, size_t ws_size,
                              hipStream_t stream) {
    const float* x     = (const float*)d_in[0];
    const int*   edges = (const int*)d_in[1];   // int32 (harness converts integer inputs)
    const int*   batch = (const int*)d_in[2];   // int32

    const int  N    = in_sizes[2];
    const long long E = in_sizes[1] / 2;
    const int  F_IN = in_sizes[0] / N;              // 128
    const int  G    = out_size / XS_STRIDE - N;     // 1000

    const float* W[3][6];
    for (int l = 0; l < 3; l++)
        for (int p = 0; p < 6; p++)
            W[l][p] = (const float*)d_in[4 + l * 6 + p];

    float* out_pool = (float*)d_out;                        // G x 192
    float* out_xs   = out_pool + (size_t)G * XS_STRIDE;     // N x 192

    const int B   = (N + 255) >> 8;                         // dst buckets (width 256)
    const int NB1 = (int)((E + CSR_CHUNK - 1) / CSR_CHUNK); // partition chunks

    // workspace layout (~26 MB)
    unsigned* ybf  = (unsigned*)d_ws;                   // N x 32 u32 (12.8 MB)
    float* stats   = (float*)(ybf + (size_t)N * 32);    // 3 x 256 floats
    int*   offsets = (int*)(stats + 3 * 256);           // N + 1
    int*   eidx    = offsets + N + 1;                   // E + 256 pad (6.4 MB)
    unsigned* ebuf = (unsigned*)(eidx + E + 256);       // E (6.4 MB)
    int*   bh      = (int*)(ebuf + E);                  // B * NB1 (~150 KB)

    const int pblocks = (N + 31) / 32;
    const int ablocks = (N + 63) / 64;

    // ---- build CSR once (shared by all 3 layers): bucketed counting sort ----
    setup_kernel<<<1, 1024, 0, stream>>>(stats, eidx + E, offsets + N, (int)E);
    p1_hist<<<NB1, 256, 0, stream>>>(edges + E, E, NB1, B, bh);
    p2_scan<<<1, 1024, 0, stream>>>(bh, B * NB1);
    p3_part<<<NB1, 256, 0, stream>>>(edges, E, NB1, B, bh, ebuf);
    p4_build<<<B, 256, 0, stream>>>(ebuf, E, NB1, B, bh, offsets, eidx, N);

    for (int l = 0; l < 3; l++) {
        const int h_off = (l == 0) ? 0 : (l - 1) * DIM;
        float* statsL = stats + l * 256;

        if (l == 0)
            proj_kernel<128, false><<<pblocks, 256, 0, stream>>>(
                x, F_IN, 0, nullptr, W[l][0], nullptr, ybf, N);
        else
            proj_kernel<64, true><<<pblocks, 256, 0, stream>>>(
                out_xs, XS_STRIDE, h_off, out_xs,
                W[l][0], stats + (l - 1) * 256 + 2 * DIM, ybf, N);

        aggmlp_kernel<<<ablocks, 256, 0, stream>>>(ybf, offsets, eidx,
            W[l][1], W[l][2], W[l][3], out_xs, l * DIM, statsL, N);

        bnparam_kernel<<<1, 64, 0, stream>>>(statsL, W[l][4], W[l][5], statsL + 2 * DIM, N);
    }

    pool_kernel<<<G, XS_STRIDE, 0, stream>>>(out_xs, batch, out_pool,
                                             stats + 2 * 256 + 2 * DIM, N);
}

// Round 11
// 453.349 us; speedup vs baseline: 4.6874x; 1.1017x over previous
//
#include <hip/hip_runtime.h>

#define DIM 64
#define XS_STRIDE 192
#define BN_EPS 1e-5f
#define B_MAX 512          // max dst buckets (N up to 131072 at W=256)
#define P4_CAP 6144        // LDS staging cap per bucket (mean 4092, 32 sigma)
#define CSR_CHUNK 16384    // edges per partition block
#define BSPACE 1280        // per-bucket extra padded space (>= 1024 + slack)

__device__ inline unsigned pack_bf16x2(float lo, float hi) {
    unsigned ulo = __float_as_uint(lo); ulo = (ulo + 0x7FFFu + ((ulo >> 16) & 1u)) >> 16;
    unsigned uhi = __float_as_uint(hi); uhi = (uhi + 0x7FFFu + ((uhi >> 16) & 1u)) >> 16;
    return ulo | (uhi << 16);
}
__device__ inline float2 unpack_bf16x2(unsigned v) {
    return make_float2(__uint_as_float(v << 16), __uint_as_float(v & 0xFFFF0000u));
}

// ---------------- setup: zero stats + ybf zero-row (row N) ----------------
__global__ void setup_kernel(float* __restrict__ stats, unsigned* __restrict__ ybf, int N) {
    int t = threadIdx.x;
    if (t < 3 * 256) stats[t] = 0.f;
    if (t < 32) ybf[(size_t)N * 32 + t] = 0u;   // zero row for gap gathers
}

// ---------------- P1: per-chunk bucket histogram ----------------
__global__ __launch_bounds__(256) void p1_hist(const int* __restrict__ dsts, long long E,
                                               int NB1, int B, int* __restrict__ bh) {
    __shared__ int hist[B_MAX];
    const int i = blockIdx.x, t = threadIdx.x;
    for (int b = t; b < B; b += 256) hist[b] = 0;
    __syncthreads();
    long long s0 = (long long)i * CSR_CHUNK;
    long long s1 = s0 + CSR_CHUNK; if (s1 > E) s1 = E;
    for (long long e = s0 + t; e < s1; e += 256)
        atomicAdd(&hist[dsts[e] >> 8], 1);
    __syncthreads();
    for (int b = t; b < B; b += 256) bh[b * NB1 + i] = hist[b];
}

// ---------------- P2: one-block exclusive scan of bh[B*NB1] ----------------
__global__ __launch_bounds__(1024) void p2_scan(int* __restrict__ bh, int total_n) {
    __shared__ int sbuf[2][1024];
    const int t = threadIdx.x;
    const int seg = (total_n + 1023) / 1024;
    int s0 = t * seg, s1 = s0 + seg; if (s1 > total_n) s1 = total_n;
    int s = 0;
    for (int i = s0; i < s1; i++) s += bh[i];
    sbuf[0][t] = s; __syncthreads();
    int c = 0;
    for (int o = 1; o < 1024; o <<= 1) {
        int val = sbuf[c][t];
        if (t >= o) val += sbuf[c][t - o];
        sbuf[c ^ 1][t] = val; __syncthreads(); c ^= 1;
    }
    int run = sbuf[c][t] - s;       // exclusive base for this thread's segment
    for (int i = s0; i < s1; i++) { int v = bh[i]; bh[i] = run; run += v; }
}

// ---------------- P3: partition edges into bucket runs (block-private, dense) ----------------
__global__ __launch_bounds__(256) void p3_part(const int* __restrict__ edges, long long E,
                                               int NB1, int B, const int* __restrict__ bh,
                                               unsigned* __restrict__ ebuf) {
    __shared__ int cur[B_MAX];
    const int i = blockIdx.x, t = threadIdx.x;
    for (int b = t; b < B; b += 256) cur[b] = bh[b * NB1 + i];
    __syncthreads();
    long long s0 = (long long)i * CSR_CHUNK;
    long long s1 = s0 + CSR_CHUNK; if (s1 > E) s1 = E;
    for (long long e = s0 + t; e < s1; e += 256) {
        int src = edges[e];
        int dst = edges[E + e];
        int b = dst >> 8;
        int pos = atomicAdd(&cur[b], 1);
        ebuf[pos] = (unsigned)src | ((unsigned)(dst & 255) << 24);
    }
}

// ---- P4: per-bucket padded CSR: node runs padded to mult-of-4 (min 4), gaps = N ----
__global__ __launch_bounds__(256) void p4_build(const unsigned* __restrict__ ebuf, long long E,
                                                int NB1, int B, const int* __restrict__ bh,
                                                int* __restrict__ offsets, int* __restrict__ psz,
                                                int* __restrict__ eidx, int N) {
    __shared__ unsigned lbuf[P4_CAP];
    __shared__ int hist[256];
    __shared__ int sbuf[2][256];
    __shared__ int cur[256];
    __shared__ int lstart[256];
    const int b = blockIdx.x, t = threadIdx.x;
    const int s = bh[b * NB1];
    const int e = (b + 1 < B) ? bh[(b + 1) * NB1] : (int)E;
    const int sz = e - s;
    const int ps = ((s + 3) & ~3) + b * BSPACE;
    const int next_raw = (b + 1 < B) ? bh[(b + 1) * NB1] : (int)E;
    const int next_ps = ((next_raw + 3) & ~3) + (b + 1) * BSPACE;
    const bool inl = (sz <= P4_CAP);
    if (inl) for (int k = t; k < sz; k += 256) lbuf[k] = ebuf[s + k];
    hist[t] = 0;
    __syncthreads();
    for (int k = t; k < sz; k += 256) {
        unsigned v = inl ? lbuf[k] : ebuf[s + k];
        atomicAdd(&hist[v >> 24], 1);
    }
    __syncthreads();
    const int deg = hist[t];
    const int pad = max(4, (deg + 3) & ~3);
    sbuf[0][t] = pad; __syncthreads();
    int c = 0;
    for (int o = 1; o < 256; o <<= 1) {
        int val = sbuf[c][t];
        if (t >= o) val += sbuf[c][t - o];
        sbuf[c ^ 1][t] = val; __syncthreads(); c ^= 1;
    }
    const int excl = sbuf[c][t] - pad;
    const int total = sbuf[c][255];
    const int node = b * 256 + t;
    if (node < N) { offsets[node] = ps + excl; psz[node] = pad; }
    lstart[t] = excl;
    cur[t] = 0;
    __syncthreads();
    for (int k = t; k < sz; k += 256) {
        unsigned v = inl ? lbuf[k] : ebuf[s + k];
        int dl = v >> 24;
        int pos = atomicAdd(&cur[dl], 1);
        eidx[ps + lstart[dl] + pos] = (int)(v & 0xFFFFFFu);
    }
    // gap fill within own node's padded run
    for (int k = deg; k < pad; k++) eidx[ps + excl + k] = N;
    __syncthreads();
    // bucket tail fill up to next bucket's padded start
    for (int i = ps + total + t; i < next_ps; i += 256) eidx[i] = N;
}

// ---- y = h @ w1 (bf16x2 packed); optional fused BN of input (write normalized back) ----
template<int DIN, bool FUSE>
__global__ __launch_bounds__(256) void proj_kernel(
    const float* __restrict__ h, int h_stride, int h_off,
    float* __restrict__ h_back,            // == h when FUSE (in-place normalize)
    const float* __restrict__ w1,
    const float* __restrict__ scsh,        // sc[64], sh[64] (for FUSE)
    unsigned* __restrict__ ybf, int N)
{
    constexpr int R = 32;
    __shared__ float w1s[DIN * DIM];
    __shared__ float hin[R][DIN];
    const int tid = threadIdx.x;
    const int row0 = blockIdx.x * R;

    for (int i = tid; i < DIN * DIM / 4; i += 256)
        *(float4*)&w1s[i * 4] = *(const float4*)&w1[i * 4];
    for (int i = tid; i < R * DIN / 4; i += 256) {
        int r = i / (DIN / 4), k4 = (i % (DIN / 4)) * 4;
        int row = row0 + r;
        float4 hv = make_float4(0.f, 0.f, 0.f, 0.f);
        if (row < N) {
            hv = *(const float4*)&h[(size_t)row * h_stride + h_off + k4];
            if (FUSE) {
                hv.x = hv.x * scsh[k4 + 0] + scsh[DIM + k4 + 0];
                hv.y = hv.y * scsh[k4 + 1] + scsh[DIM + k4 + 1];
                hv.z = hv.z * scsh[k4 + 2] + scsh[DIM + k4 + 2];
                hv.w = hv.w * scsh[k4 + 3] + scsh[DIM + k4 + 3];
                *(float4*)&h_back[(size_t)row * h_stride + h_off + k4] = hv;
            }
        }
        *(float4*)&hin[r][k4] = hv;
    }
    __syncthreads();

    const int hw = tid >> 5;       // half-wave 0..7 owns rows hw*4..hw*4+3
    const int hl = tid & 31;       // cols 2*hl, 2*hl+1
    float a0[4], a1[4];
    #pragma unroll
    for (int q = 0; q < 4; q++) { a0[q] = 0.f; a1[q] = 0.f; }
    for (int k = 0; k < DIN; k++) {
        float w0 = w1s[k * DIM + 2 * hl];
        float w1v = w1s[k * DIM + 2 * hl + 1];
        #pragma unroll
        for (int q = 0; q < 4; q++) {
            float hv = hin[hw * 4 + q][k];
            a0[q] += hv * w0; a1[q] += hv * w1v;
        }
    }
    #pragma unroll
    for (int q = 0; q < 4; q++) {
        int row = row0 + hw * 4 + q;
        if (row < N) ybf[(size_t)row * 32 + hl] = pack_bf16x2(a0[q], a1[q]);
    }
}

// ---- fused: quarter-wave (16 lanes, uint2) walks 4 rows, int4 eidx, zero-row gaps ----
__global__ __launch_bounds__(256) void aggmlp_kernel(
    const unsigned* __restrict__ ybf,
    const int* __restrict__ offsets, const int* __restrict__ psz,
    const int* __restrict__ eidx,
    const float* __restrict__ b1,
    const float* __restrict__ w2, const float* __restrict__ b2,
    float* __restrict__ xs, int xs_off,
    float* __restrict__ stats, int N)
{
    constexpr int R = 64;
    __shared__ float zin[R][DIM];        // 16KB
    __shared__ float sred[2][DIM];
    const int tid  = threadIdx.x;
    const int row0 = blockIdx.x * R;
    const int qw = tid >> 4;             // quarter-wave 0..15 owns rows qw*4..qw*4+3
    const int ql = tid & 15;             // feats 4*ql..4*ql+3
    const uint2* __restrict__ ybf2 = (const uint2*)ybf;

    if (tid < DIM) { sred[0][tid] = 0.f; sred[1][tid] = 0.f; }

    const float4 b1v = *(const float4*)&b1[ql * 4];
    int p0[4], sz[4];
    float ac[4][4];
    #pragma unroll
    for (int q = 0; q < 4; q++) {
        int node = row0 + qw * 4 + q;
        if (node < N) {
            p0[q] = offsets[node];
            sz[q] = psz[node];
            uint2 sv = ybf2[(size_t)node * 16 + ql];
            float2 lo = unpack_bf16x2(sv.x), hi = unpack_bf16x2(sv.y);
            ac[q][0] = lo.x + b1v.x; ac[q][1] = lo.y + b1v.y;
            ac[q][2] = hi.x + b1v.z; ac[q][3] = hi.y + b1v.w;
        } else {
            p0[q] = 0; sz[q] = 0;
            ac[q][0] = ac[q][1] = ac[q][2] = ac[q][3] = 0.f;
        }
    }
    int steps = 0;
    #pragma unroll
    for (int q = 0; q < 4; q++) steps = max(steps, sz[q] >> 2);

    for (int s = 0; s < steps; s++) {
        const int b4 = 4 * s;
        int4 e4[4];
        #pragma unroll
        for (int q = 0; q < 4; q++) {
            int off = max(0, min(b4, sz[q] - 4));   // clamp into own padded run
            e4[q] = *(const int4*)&eidx[p0[q] + off];
        }
        uint2 g[4][4];
        #pragma unroll
        for (int q = 0; q < 4; q++) {
            g[q][0] = ybf2[(size_t)e4[q].x * 16 + ql];
            g[q][1] = ybf2[(size_t)e4[q].y * 16 + ql];
            g[q][2] = ybf2[(size_t)e4[q].z * 16 + ql];
            g[q][3] = ybf2[(size_t)e4[q].w * 16 + ql];
        }
        #pragma unroll
        for (int q = 0; q < 4; q++) {
            const float m = (b4 < sz[q]) ? 1.f : 0.f;
            #pragma unroll
            for (int j = 0; j < 4; j++) {
                float2 lo = unpack_bf16x2(g[q][j].x), hi = unpack_bf16x2(g[q][j].y);
                ac[q][0] += lo.x * m; ac[q][1] += lo.y * m;
                ac[q][2] += hi.x * m; ac[q][3] += hi.y * m;
            }
        }
    }
    #pragma unroll
    for (int q = 0; q < 4; q++) {
        int r = qw * 4 + q;
        float4 z;
        z.x = fmaxf(ac[q][0], 0.f); z.y = fmaxf(ac[q][1], 0.f);
        z.z = fmaxf(ac[q][2], 0.f); z.w = fmaxf(ac[q][3], 0.f);   // relu between layers
        *(float4*)&zin[r][ql * 4] = z;
    }
    __syncthreads();

    // GEMM: relu(z) @ w2 + b2, register-tiled (16 rows/thread); w2 from global (L1-hot)
    const int lane = tid & 63;
    const int wv_  = tid >> 6;
    float oacc[16];
    #pragma unroll
    for (int i = 0; i < 16; i++) oacc[i] = b2[lane];
    for (int k = 0; k < DIM; k++) {
        float w = w2[k * DIM + lane];
        #pragma unroll
        for (int i = 0; i < 16; i++) oacc[i] += zin[wv_ + 4 * i][k] * w;
    }
    float s1 = 0.f, s2 = 0.f;
    #pragma unroll
    for (int i = 0; i < 16; i++) {
        int row = row0 + wv_ + 4 * i;
        if (row < N) {
            float v = fmaxf(oacc[i], 0.f);   // F.relu after conv
            xs[(size_t)row * XS_STRIDE + xs_off + lane] = v;
            s1 += v; s2 += v * v;
        }
    }
    atomicAdd(&sred[0][lane], s1);
    atomicAdd(&sred[1][lane], s2);
    __syncthreads();
    if (tid < DIM) {
        atomicAdd(&stats[tid], sred[0][tid]);
        atomicAdd(&stats[DIM + tid], sred[1][tid]);
    }
}

// ---------------- BN params: scale/shift from sum/sumsq ----------------
__global__ void bnparam_kernel(const float* __restrict__ stats,
                               const float* __restrict__ gamma, const float* __restrict__ beta,
                               float* __restrict__ sc, int N) {
    int c = threadIdx.x;  // 64 threads
    float inv_n = 1.0f / (float)N;
    float mean = stats[c] * inv_n;
    float var  = stats[DIM + c] * inv_n - mean * mean;
    float scale = gamma[c] * rsqrtf(var + BN_EPS);
    sc[c] = scale;
    sc[DIM + c] = beta[c] - mean * scale;
}

// ---- per-graph pooling; also applies layer-2 BN inline (cols 128..191) + write-back ----
__global__ void pool_kernel(float* __restrict__ xs, const int* __restrict__ batch,
                            float* __restrict__ pool, const float* __restrict__ scsh2, int N) {
    int g = blockIdx.x;
    int tid = threadIdx.x;  // 192 threads
    int lo = 0, hi = N;
    while (lo < hi) { int mid = (lo + hi) >> 1; if (batch[mid] < g) lo = mid + 1; else hi = mid; }
    int start = lo;
    hi = N;
    while (lo < hi) { int mid = (lo + hi) >> 1; if (batch[mid] < g + 1) lo = mid + 1; else hi = mid; }
    int end = lo;
    float s = 0.f;
    if (tid < 2 * DIM) {
        for (int n = start; n < end; n++) s += xs[(size_t)n * XS_STRIDE + tid];
    } else {
        const float sc = scsh2[tid - 2 * DIM];
        const float sh = scsh2[DIM + tid - 2 * DIM];
        for (int n = start; n < end; n++) {
            size_t p = (size_t)n * XS_STRIDE + tid;
            float v = xs[p] * sc + sh;     // layer-2 BN applied here
            xs[p] = v;
            s += v;
        }
    }
    pool[(size_t)g * XS_STRIDE + tid] = s;
}

extern "C" void kernel_launch(void* const* d_in, const int* in_sizes, int n_in,
                              void* d_out, int out_size, void* d_ws, size_t ws_size,
                              hipStream_t stream) {
    const float* x     = (const float*)d_in[0];
    const int*   edges = (const int*)d_in[1];   // int32 (harness converts integer inputs)
    const int*   batch = (const int*)d_in[2];   // int32

    const int  N    = in_sizes[2];
    const long long E = in_sizes[1] / 2;
    const int  F_IN = in_sizes[0] / N;              // 128
    const int  G    = out_size / XS_STRIDE - N;     // 1000

    const float* W[3][6];
    for (int l = 0; l < 3; l++)
        for (int p = 0; p < 6; p++)
            W[l][p] = (const float*)d_in[4 + l * 6 + p];

    float* out_pool = (float*)d_out;                        // G x 192
    float* out_xs   = out_pool + (size_t)G * XS_STRIDE;     // N x 192

    const int B   = (N + 255) >> 8;                         // dst buckets (width 256)
    const int NB1 = (int)((E + CSR_CHUNK - 1) / CSR_CHUNK); // partition chunks
    const int EPAD = (int)(((E + 3) & ~3LL) + (long long)B * BSPACE + 64);

    // workspace layout (~27 MB)
    unsigned* ybf  = (unsigned*)d_ws;                   // (N+1) x 32 u32 (12.8 MB)
    float* stats   = (float*)(ybf + (size_t)(N + 1) * 32);  // 3 x 256 floats
    int*   offsets = (int*)(stats + 3 * 256);           // N
    int*   psz     = offsets + N + 1;                   // N
    int*   eidx    = psz + N;                           // EPAD (~7 MB)
    unsigned* ebuf = (unsigned*)(eidx + EPAD);          // E (6.4 MB)
    int*   bh      = (int*)(ebuf + E);                  // B * NB1 (~150 KB)

    const int pblocks = (N + 31) / 32;
    const int ablocks = (N + 63) / 64;

    // ---- build padded CSR once (shared by all 3 layers) ----
    setup_kernel<<<1, 1024, 0, stream>>>(stats, ybf, N);
    p1_hist<<<NB1, 256, 0, stream>>>(edges + E, E, NB1, B, bh);
    p2_scan<<<1, 1024, 0, stream>>>(bh, B * NB1);
    p3_part<<<NB1, 256, 0, stream>>>(edges, E, NB1, B, bh, ebuf);
    p4_build<<<B, 256, 0, stream>>>(ebuf, E, NB1, B, bh, offsets, psz, eidx, N);

    for (int l = 0; l < 3; l++) {
        const int h_off = (l == 0) ? 0 : (l - 1) * DIM;
        float* statsL = stats + l * 256;

        if (l == 0)
            proj_kernel<128, false><<<pblocks, 256, 0, stream>>>(
                x, F_IN, 0, nullptr, W[l][0], nullptr, ybf, N);
        else
            proj_kernel<64, true><<<pblocks, 256, 0, stream>>>(
                out_xs, XS_STRIDE, h_off, out_xs,
                W[l][0], stats + (l - 1) * 256 + 2 * DIM, ybf, N);

        aggmlp_kernel<<<ablocks, 256, 0, stream>>>(ybf, offsets, psz, eidx,
            W[l][1], W[l][2], W[l][3], out_xs, l * DIM, statsL, N);

        bnparam_kernel<<<1, 64, 0, stream>>>(statsL, W[l][4], W[l][5], statsL + 2 * DIM, N);
    }

    pool_kernel<<<G, XS_STRIDE, 0, stream>>>(out_xs, batch, out_pool,
                                             stats + 2 * 256 + 2 * DIM, N);
}